// Round 2
// baseline (382.559 us; speedup 1.0000x reference)
//
#include <hip/hip_runtime.h>
#include <hip/hip_bf16.h>
#include <stdint.h>

// Problem constants (hard-coded): B=4, S=2048, D=1024, H=16, HD=64
#define B_   4
#define S_   2048
#define D_   1024
#define H_   16
#define HD_  64
#define BH_  (B_*H_)      // 64
#define MROWS (B_*S_)     // 8192

typedef short  short8  __attribute__((ext_vector_type(8)));
typedef float  floatx4 __attribute__((ext_vector_type(4)));

__device__ __forceinline__ ushort f2bf(float f) {
    union { float f; uint32_t u; } v; v.f = f;
    uint32_t u = v.u;
    return (ushort)((u + 0x7FFFu + ((u >> 16) & 1u)) >> 16);   // RNE
}
__device__ __forceinline__ float u2f(uint32_t u) {
    union { uint32_t u; float f; } v; v.u = u; return v.f;
}
__device__ __forceinline__ uint32_t f2u(float f) {
    union { float f; uint32_t u; } v; v.f = f; return v.u;
}

// async global->LDS, 16 B per lane. LDS dest MUST be wave-uniform base +
// lane*16 (m104/m108) — any swizzling must happen on the GLOBAL address.
__device__ __forceinline__ void gl_lds16(const ushort* g, ushort* l) {
    __builtin_amdgcn_global_load_lds(
        (const __attribute__((address_space(1))) unsigned int*)g,
        (__attribute__((address_space(3))) unsigned int*)l,
        16, 0, 0);
}

// ---------------------------------------------------------------- fused prep
// blocks [0,3072): Wqkv^T->bf16 ; [3072,4096): Wout^T->bf16 ; [4096,12288): x->bf16
__global__ __launch_bounds__(256)
void k_prep(const float* __restrict__ x, const float* __restrict__ Wqkv,
            const float* __restrict__ Wout,
            ushort* __restrict__ Xbf, ushort* __restrict__ WqkvT, ushort* __restrict__ WoutT) {
    __shared__ float tile[32][33];
    int blk = blockIdx.x;
    int tid = threadIdx.x;
    if (blk >= 4096) {
        int i = (blk - 4096) * 1024 + tid * 4;
        float4 f = *(const float4*)(x + i);
        ushort4 o; o.x = f2bf(f.x); o.y = f2bf(f.y); o.z = f2bf(f.z); o.w = f2bf(f.w);
        *(ushort4*)(Xbf + i) = o;
        return;
    }
    const float* in; ushort* out; int R, C, bx, by;
    if (blk < 3072) { in = Wqkv; out = WqkvT; R = D_; C = 3 * D_; bx = (blk % 96) * 32; by = (blk / 96) * 32; }
    else            { int b2 = blk - 3072; in = Wout; out = WoutT; R = D_; C = D_; bx = (b2 % 32) * 32; by = (b2 / 32) * 32; }
    int tx = tid & 31, ty = tid >> 5;
    #pragma unroll
    for (int j = 0; j < 32; j += 8)
        tile[ty + j][tx] = in[(size_t)(by + ty + j) * C + bx + tx];
    __syncthreads();
    #pragma unroll
    for (int j = 0; j < 32; j += 8)
        out[(size_t)(bx + ty + j) * R + by + tx] = f2bf(tile[tx][ty + j]);
}

// ---------------------------------------------------------------- GEMM (async + global-side XOR swizzle)
#define BM 128
#define BN 128
#define BK 64

template<int EPI>
__global__ __launch_bounds__(256)
void k_gemm(const ushort* __restrict__ A, const ushort* __restrict__ Bt,
            float* __restrict__ outF,
            ushort* __restrict__ q_out, ushort* __restrict__ k_out, ushort* __restrict__ v_out,
            int M, int N, int K) {
    __shared__ __align__(16) ushort As[BM * 64];
    __shared__ __align__(16) ushort Bs[BN * 64];
    int tid  = threadIdx.x;
    int lane = tid & 63;
    int wave = tid >> 6;
    int quad = lane >> 4;
    int l16  = lane & 15;
    int bm = blockIdx.y * BM;
    int bn = blockIdx.x * BN;
    int wm = (wave >> 1) * 64;
    int wn = (wave & 1) * 64;

    floatx4 acc[4][4] = {};

    for (int k0 = 0; k0 < K; k0 += BK) {
        __syncthreads();
        #pragma unroll
        for (int i = 0; i < 4; i++) {
            int c   = i * 256 + tid;
            int row = c >> 3;
            int gc  = (c & 7) ^ (row & 7);    // permuted global chunk
            gl_lds16(&A[(size_t)(bm + row) * K + k0 + gc * 8],  &As[c * 8]);
            gl_lds16(&Bt[(size_t)(bn + row) * K + k0 + gc * 8], &Bs[c * 8]);
        }
        __syncthreads();
        #pragma unroll
        for (int kk = 0; kk < 2; kk++) {
            short8 af[4], bf[4];
            #pragma unroll
            for (int mt = 0; mt < 4; mt++)
                af[mt] = *(const short8*)&As[(wm + mt * 16 + l16) * 64 +
                                             (((kk * 4 + quad) ^ (l16 & 7)) << 3)];
            #pragma unroll
            for (int nt = 0; nt < 4; nt++)
                bf[nt] = *(const short8*)&Bs[(wn + nt * 16 + l16) * 64 +
                                             (((kk * 4 + quad) ^ (l16 & 7)) << 3)];
            #pragma unroll
            for (int mt = 0; mt < 4; mt++)
                #pragma unroll
                for (int nt = 0; nt < 4; nt++)
                    acc[mt][nt] = __builtin_amdgcn_mfma_f32_16x16x32_bf16(af[mt], bf[nt], acc[mt][nt], 0, 0, 0);
        }
    }

    #pragma unroll
    for (int mt = 0; mt < 4; mt++)
        #pragma unroll
        for (int nt = 0; nt < 4; nt++)
            #pragma unroll
            for (int r = 0; r < 4; r++) {
                int row = bm + wm + mt * 16 + quad * 4 + r;
                int col = bn + wn + nt * 16 + l16;
                float v = acc[mt][nt][r];
                if (EPI == 0) {
                    int which = col >> 10;
                    int rem   = col & 1023;
                    int h  = rem >> 6, hd = rem & 63;
                    int b  = row >> 11, s  = row & 2047;
                    size_t idx = ((size_t)(b * H_ + h) * S_ + s) * HD_ + hd;
                    ushort bv = f2bf(v);
                    ushort* dst = (which == 0) ? q_out : (which == 1) ? k_out : v_out;
                    dst[idx] = bv;
                } else {
                    outF[(size_t)row * N + col] = v;
                }
            }
}

// ---------------------------------------------------------------- fused RoPE + V-transpose
// blocks [0,32768): in-place RoPE on Q (pre-scaled by 0.125*log2(e)) and K.
// blocks [32768,34816): V [bh][s][HD] -> VbT [bh][HD][S].
__global__ __launch_bounds__(256)
void k_ropevt(ushort* __restrict__ Q, ushort* __restrict__ Kv,
              const ushort* __restrict__ Vb, ushort* __restrict__ VbT,
              const float* __restrict__ cosT, const float* __restrict__ sinT) {
    __shared__ __align__(16) ushort t[64 * 72];
    int blk = blockIdx.x;
    int tid = threadIdx.x;
    if (blk < 32768) {
        int wid  = (blk * 256 + tid) >> 6;
        int lane = tid & 63;
        int s  = wid & (S_ - 1);
        int bh = wid >> 11;
        int i  = lane & 31;
        float c  = cosT[s * 32 + i];
        float sn = sinT[s * 32 + i];
        size_t base = ((size_t)bh * S_ + s) * HD_;

        uint32_t uq = *(const uint32_t*)&Q[base + 2 * i];
        float x1 = u2f(uq << 16), x2 = u2f(uq & 0xFFFF0000u);
        float o  = (lane < 32) ? (x1 * c - x2 * sn) : (x1 * sn + x2 * c);
        Q[base + lane] = f2bf(o * 0.1803368801f);   // (1/8)*log2(e)

        uint32_t uk = *(const uint32_t*)&Kv[base + 2 * i];
        x1 = u2f(uk << 16); x2 = u2f(uk & 0xFFFF0000u);
        o  = (lane < 32) ? (x1 * c - x2 * sn) : (x1 * sn + x2 * c);
        Kv[base + lane] = f2bf(o);
        return;
    }
    int b2 = blk - 32768;
    int bh = b2 >> 5;
    int s0 = (b2 & 31) * 64;
    int ss = tid >> 2, c0 = (tid & 3) * 16;
    size_t base = (size_t)bh * S_ * HD_;
    *(uint4*)&t[ss * 72 + c0]     = *(const uint4*)&Vb[base + (size_t)(s0 + ss) * HD_ + c0];
    *(uint4*)&t[ss * 72 + c0 + 8] = *(const uint4*)&Vb[base + (size_t)(s0 + ss) * HD_ + c0 + 8];
    __syncthreads();
    int hd = tid >> 2, q0 = (tid & 3) * 16;
    ushort tmp[16];
    #pragma unroll
    for (int e = 0; e < 16; e++) tmp[e] = t[(q0 + e) * 72 + hd];
    size_t obase = (size_t)bh * HD_ * S_ + (size_t)hd * S_ + s0 + q0;
    *(uint4*)&VbT[obase]     = *(const uint4*)&tmp[0];
    *(uint4*)&VbT[obase + 8] = *(const uint4*)&tmp[8];
}

// ---------------------------------------------------------------- flash attention v10
// Post-mortem v9: __launch_bounds__(512,8) forced regs<=64 -> scratch spill
// (FETCH/WRITE both +20MB). v10 keeps 512 threads / 8 waves but:
//  - 2 m-blocks per wave (rows qb0+w*16 and qb0+128+w*16): block covers 256
//    q-rows, grid halves to 512 -> total K/V staging tiles/bh drop 272->144,
//    vb fragments amortized over 2 m again.
//  - single-barrier double-buffered prefetch: issue next tile's
//    global_load_lds right after the barrier, compute current buffer; the
//    compiler's vmcnt(0) drain lands at the NEXT barrier, so staging latency
//    hides under compute (T3-minimum 2-phase). One barrier/tile, not two.
//  - kt-outer QK: kf fragment loaded once, shared by both m (8 vs 16
//    ds_read_b128 per tile-wave); sc becomes [2][4].
//  - __launch_bounds__(512,4): regs<=128 (natural use ~120), no spill.
// grid: 512 blocks = 8 strip-groups x 64 bh; strips paired {7,0},{6,1},
// {5,2},{4,3} across the two dispatch passes -> 36 tiles per CU stratum.
__global__ __launch_bounds__(512, 4)
void k_attn(const ushort* __restrict__ Q, const ushort* __restrict__ K,
            const ushort* __restrict__ VT, ushort* __restrict__ O) {
    __shared__ __align__(16) ushort Ks[2][64 * 64];    // [buf][key][hd]  swizzled
    __shared__ __align__(16) ushort Vt[2][64 * 64];    // [buf][hd][key]  swizzled
    __shared__ __align__(16) ushort Pst[8][32 * 64];   // per-wave [qrow][key] swizzled

    const int PI[8] = {7,6,5,4, 0,1,2,3};

    int tid  = threadIdx.x;
    int lane = tid & 63;
    int wave = tid >> 6;
    int quad = lane >> 4;
    int l16  = lane & 15;

    int bh   = blockIdx.x & 63;
    int qblk = PI[blockIdx.x >> 6];
    int qb0  = qblk * 256;
    size_t hbase = (size_t)bh * S_ * HD_;
    size_t vbase = (size_t)bh * HD_ * S_;

    int mrow[2] = { qb0 + wave * 16, qb0 + 128 + wave * 16 };

    short8 qf[2][2];
    #pragma unroll
    for (int m = 0; m < 2; m++)
        #pragma unroll
        for (int h = 0; h < 2; h++)
            qf[m][h] = *(const short8*)&Q[hbase + (size_t)(mrow[m] + l16) * HD_ + quad * 8 + h * 32];

    short8 ones;
    #pragma unroll
    for (int e = 0; e < 8; e++) ones[e] = (short)0x3F80;   // bf16 1.0

    floatx4 acc[2][4] = {};
    floatx4 accl[2] = {};

    // staging pointers: 512 threads stage the full 64x64 K-tile and V-tile
    // with one 16B chunk each; advance by constant per tile.
    int srow = tid >> 3;                 // chunk row (0..63)
    const ushort* kp = &K[hbase + (size_t)srow * HD_ + (((tid & 7) ^ (srow & 7)) << 3)];
    const ushort* vp = &VT[vbase + (size_t)srow * S_ + (((tid & 7) ^ (srow & 7)) << 3)];

    int nk = 4 * qblk + 4;

    // prologue: stage tile 0 into buffer 0
    gl_lds16(kp, &Ks[0][tid * 8]);
    gl_lds16(vp, &Vt[0][tid * 8]);

    for (int kb = 0; kb < nk; kb++) {
        int cur = kb & 1;
        int k0  = kb * 64;
        __syncthreads();                 // vmcnt(0) drained here -> buf[cur] ready
        if (kb + 1 < nk) {               // issue next tile's loads; they fly
            kp += 64 * HD_; vp += 64;    // under this tile's compute
            gl_lds16(kp, &Ks[cur ^ 1][tid * 8]);
            gl_lds16(vp, &Vt[cur ^ 1][tid * 8]);
        }

        bool act[2] = { k0 <= mrow[0] + 15, k0 <= mrow[1] + 15 };  // act[0]=>act[1]
        if (!act[1]) continue;           // wave-uniform: both inactive

        // ---- QK (swapped operands: lane col = q row), kf shared across m
        floatx4 sc[2][4];
        #pragma unroll
        for (int m = 0; m < 2; m++)
            if (act[m])
                #pragma unroll
                for (int kt = 0; kt < 4; kt++)
                    sc[m][kt] = (floatx4){0.f, 0.f, 0.f, 0.f};

        __builtin_amdgcn_s_setprio(1);
        #pragma unroll
        for (int kt = 0; kt < 4; kt++)
            #pragma unroll
            for (int h = 0; h < 2; h++) {
                short8 kf = *(const short8*)&Ks[cur][(kt * 16 + l16) * 64 +
                                                     (((h * 4 + quad) ^ (l16 & 7)) << 3)];
                #pragma unroll
                for (int m = 0; m < 2; m++)
                    if (act[m])
                        sc[m][kt] = __builtin_amdgcn_mfma_f32_16x16x32_bf16(kf, qf[m][h], sc[m][kt], 0, 0, 0);
            }
        __builtin_amdgcn_s_setprio(0);

        // ---- exp2 + mask + packed swizzled P store (cvt_pk RNE)
        #pragma unroll
        for (int m = 0; m < 2; m++) {
            if (!act[m]) continue;
            bool needMask = (k0 + 63 > mrow[m]);
            int qr = mrow[m] + l16;
            #pragma unroll
            for (int kt = 0; kt < 4; kt++) {
                float p[4];
                #pragma unroll
                for (int r = 0; r < 4; r++) {
                    float v = exp2f(sc[m][kt][r]);
                    if (needMask) {
                        int kc = k0 + kt * 16 + quad * 4 + r;
                        if (kc > qr) v = 0.0f;
                    }
                    p[r] = v;
                }
                uint2 pk;
                asm("v_cvt_pk_bf16_f32 %0, %1, %2" : "=v"(pk.x) : "v"(p[0]), "v"(p[1]));
                asm("v_cvt_pk_bf16_f32 %0, %1, %2" : "=v"(pk.y) : "v"(p[2]), "v"(p[3]));
                int pc = (kt * 4 + quad) ^ (l16 & 14);
                *(uint2*)&Pst[wave][(m * 16 + l16) * 64 + pc * 4] = pk;
            }
        }

        // ---- PV (+ MFMA-pipe row sums), vb shared across m
        #pragma unroll
        for (int k2 = 0; k2 < 2; k2++) {
            short8 vb[4];
            #pragma unroll
            for (int nt = 0; nt < 4; nt++)
                vb[nt] = *(const short8*)&Vt[cur][(nt * 16 + l16) * 64 +
                                                  (((k2 * 4 + quad) ^ (l16 & 7)) << 3)];
            int pe = (k2 * 8 + quad * 2) ^ (l16 & 14);
            __builtin_amdgcn_s_setprio(1);
            #pragma unroll
            for (int m = 0; m < 2; m++) {
                if (!act[m]) continue;
                short8 pa = *(const short8*)&Pst[wave][(m * 16 + l16) * 64 + pe * 4];
                #pragma unroll
                for (int nt = 0; nt < 4; nt++)
                    acc[m][nt] = __builtin_amdgcn_mfma_f32_16x16x32_bf16(pa, vb[nt], acc[m][nt], 0, 0, 0);
                accl[m] = __builtin_amdgcn_mfma_f32_16x16x32_bf16(pa, ones, accl[m], 0, 0, 0);
            }
            __builtin_amdgcn_s_setprio(0);
        }
    }

    int b = bh >> 4, h = bh & 15;
    #pragma unroll
    for (int m = 0; m < 2; m++)
        #pragma unroll
        for (int r = 0; r < 4; r++) {
            float inv = 1.0f / accl[m][r];
            int qr = mrow[m] + quad * 4 + r;
            #pragma unroll
            for (int nt = 0; nt < 4; nt++)
                O[((size_t)(b * S_ + qr)) * D_ + h * HD_ + nt * 16 + l16] = f2bf(acc[m][nt][r] * inv);
        }
}

// ---------------------------------------------------------------- launch
extern "C" void kernel_launch(void* const* d_in, const int* in_sizes, int n_in,
                              void* d_out, int out_size, void* d_ws, size_t ws_size,
                              hipStream_t stream) {
    const float* x    = (const float*)d_in[0];
    const float* cosT = (const float*)d_in[1];
    const float* sinT = (const float*)d_in[2];
    // d_in[3] = mask : causal, computed analytically — never read
    const float* Wqkv = (const float*)d_in[4];
    const float* Wout = (const float*)d_in[5];
    float* out = (float*)d_out;

    ushort* ws = (ushort*)d_ws;
    ushort* Xbf    = ws;                           // 8192*1024 (dead after GEMM0)
    ushort* WqkvT  = Xbf    + (size_t)MROWS * D_;  // 3072*1024
    ushort* WoutT  = WqkvT  + (size_t)3 * D_ * D_; // 1024*1024
    ushort* Qb     = WoutT  + (size_t)D_ * D_;     // 64*2048*64
    ushort* Kb     = Qb     + (size_t)BH_ * S_ * HD_;
    ushort* Vb     = Kb     + (size_t)BH_ * S_ * HD_;
    ushort* VbT    = Vb     + (size_t)BH_ * S_ * HD_;
    ushort* AO     = Xbf;                          // alias: Xbf dead after GEMM0

    k_prep<<<12288, 256, 0, stream>>>(x, Wqkv, Wout, Xbf, WqkvT, WoutT);
    k_gemm<0><<<dim3(3 * D_ / BN, MROWS / BM), 256, 0, stream>>>(Xbf, WqkvT, nullptr, Qb, Kb, Vb,
                                                                 MROWS, 3 * D_, D_);
    k_ropevt<<<34816, 256, 0, stream>>>(Qb, Kb, Vb, VbT, cosT, sinT);
    k_attn<<<512, 512, 0, stream>>>(Qb, Kb, VbT, AO);
    k_gemm<1><<<dim3(D_ / BN, MROWS / BM), 256, 0, stream>>>(AO, WoutT, out, nullptr, nullptr, nullptr,
                                                             MROWS, D_, D_);
}

// Round 3
// 300.520 us; speedup vs baseline: 1.2730x; 1.2730x over previous
//
#include <hip/hip_runtime.h>
#include <hip/hip_bf16.h>
#include <stdint.h>

// Problem constants (hard-coded): B=4, S=2048, D=1024, H=16, HD=64
#define B_   4
#define S_   2048
#define D_   1024
#define H_   16
#define HD_  64
#define BH_  (B_*H_)      // 64
#define MROWS (B_*S_)     // 8192

typedef short  short8  __attribute__((ext_vector_type(8)));
typedef float  floatx4 __attribute__((ext_vector_type(4)));

__device__ __forceinline__ ushort f2bf(float f) {
    union { float f; uint32_t u; } v; v.f = f;
    uint32_t u = v.u;
    return (ushort)((u + 0x7FFFu + ((u >> 16) & 1u)) >> 16);   // RNE
}
__device__ __forceinline__ float u2f(uint32_t u) {
    union { uint32_t u; float f; } v; v.u = u; return v.f;
}
__device__ __forceinline__ uint32_t f2u(float f) {
    union { float f; uint32_t u; } v; v.f = f; return v.u;
}

// async global->LDS, 16 B per lane. LDS dest MUST be wave-uniform base +
// lane*16 (m104/m108) — any swizzling must happen on the GLOBAL address.
__device__ __forceinline__ void gl_lds16(const ushort* g, ushort* l) {
    __builtin_amdgcn_global_load_lds(
        (const __attribute__((address_space(1))) unsigned int*)g,
        (__attribute__((address_space(3))) unsigned int*)l,
        16, 0, 0);
}

// ---------------------------------------------------------------- fused prep
// blocks [0,3072): Wqkv^T->bf16 ; [3072,4096): Wout^T->bf16 ; [4096,12288): x->bf16
__global__ __launch_bounds__(256)
void k_prep(const float* __restrict__ x, const float* __restrict__ Wqkv,
            const float* __restrict__ Wout,
            ushort* __restrict__ Xbf, ushort* __restrict__ WqkvT, ushort* __restrict__ WoutT) {
    __shared__ float tile[32][33];
    int blk = blockIdx.x;
    int tid = threadIdx.x;
    if (blk >= 4096) {
        int i = (blk - 4096) * 1024 + tid * 4;
        float4 f = *(const float4*)(x + i);
        ushort4 o; o.x = f2bf(f.x); o.y = f2bf(f.y); o.z = f2bf(f.z); o.w = f2bf(f.w);
        *(ushort4*)(Xbf + i) = o;
        return;
    }
    const float* in; ushort* out; int R, C, bx, by;
    if (blk < 3072) { in = Wqkv; out = WqkvT; R = D_; C = 3 * D_; bx = (blk % 96) * 32; by = (blk / 96) * 32; }
    else            { int b2 = blk - 3072; in = Wout; out = WoutT; R = D_; C = D_; bx = (b2 % 32) * 32; by = (b2 / 32) * 32; }
    int tx = tid & 31, ty = tid >> 5;
    #pragma unroll
    for (int j = 0; j < 32; j += 8)
        tile[ty + j][tx] = in[(size_t)(by + ty + j) * C + bx + tx];
    __syncthreads();
    #pragma unroll
    for (int j = 0; j < 32; j += 8)
        out[(size_t)(bx + ty + j) * R + by + tx] = f2bf(tile[tx][ty + j]);
}

// ---------------------------------------------------------------- GEMM (async + global-side XOR swizzle)
#define BM 128
#define BN 128
#define BK 64

template<int EPI>
__global__ __launch_bounds__(256)
void k_gemm(const ushort* __restrict__ A, const ushort* __restrict__ Bt,
            float* __restrict__ outF,
            ushort* __restrict__ q_out, ushort* __restrict__ k_out, ushort* __restrict__ v_out,
            int M, int N, int K) {
    __shared__ __align__(16) ushort As[BM * 64];
    __shared__ __align__(16) ushort Bs[BN * 64];
    int tid  = threadIdx.x;
    int lane = tid & 63;
    int wave = tid >> 6;
    int quad = lane >> 4;
    int l16  = lane & 15;
    int bm = blockIdx.y * BM;
    int bn = blockIdx.x * BN;
    int wm = (wave >> 1) * 64;
    int wn = (wave & 1) * 64;

    floatx4 acc[4][4] = {};

    for (int k0 = 0; k0 < K; k0 += BK) {
        __syncthreads();
        #pragma unroll
        for (int i = 0; i < 4; i++) {
            int c   = i * 256 + tid;
            int row = c >> 3;
            int gc  = (c & 7) ^ (row & 7);    // permuted global chunk
            gl_lds16(&A[(size_t)(bm + row) * K + k0 + gc * 8],  &As[c * 8]);
            gl_lds16(&Bt[(size_t)(bn + row) * K + k0 + gc * 8], &Bs[c * 8]);
        }
        __syncthreads();
        #pragma unroll
        for (int kk = 0; kk < 2; kk++) {
            short8 af[4], bf[4];
            #pragma unroll
            for (int mt = 0; mt < 4; mt++)
                af[mt] = *(const short8*)&As[(wm + mt * 16 + l16) * 64 +
                                             (((kk * 4 + quad) ^ (l16 & 7)) << 3)];
            #pragma unroll
            for (int nt = 0; nt < 4; nt++)
                bf[nt] = *(const short8*)&Bs[(wn + nt * 16 + l16) * 64 +
                                             (((kk * 4 + quad) ^ (l16 & 7)) << 3)];
            #pragma unroll
            for (int mt = 0; mt < 4; mt++)
                #pragma unroll
                for (int nt = 0; nt < 4; nt++)
                    acc[mt][nt] = __builtin_amdgcn_mfma_f32_16x16x32_bf16(af[mt], bf[nt], acc[mt][nt], 0, 0, 0);
        }
    }

    #pragma unroll
    for (int mt = 0; mt < 4; mt++)
        #pragma unroll
        for (int nt = 0; nt < 4; nt++)
            #pragma unroll
            for (int r = 0; r < 4; r++) {
                int row = bm + wm + mt * 16 + quad * 4 + r;
                int col = bn + wn + nt * 16 + l16;
                float v = acc[mt][nt][r];
                if (EPI == 0) {
                    int which = col >> 10;
                    int rem   = col & 1023;
                    int h  = rem >> 6, hd = rem & 63;
                    int b  = row >> 11, s  = row & 2047;
                    size_t idx = ((size_t)(b * H_ + h) * S_ + s) * HD_ + hd;
                    ushort bv = f2bf(v);
                    ushort* dst = (which == 0) ? q_out : (which == 1) ? k_out : v_out;
                    dst[idx] = bv;
                } else {
                    outF[(size_t)row * N + col] = v;
                }
            }
}

// ---------------------------------------------------------------- fused RoPE + V-transpose
// blocks [0,32768): in-place RoPE on Q (pre-scaled by 0.125*log2(e)) and K.
// blocks [32768,34816): V [bh][s][HD] -> VbT [bh][HD][S].
__global__ __launch_bounds__(256)
void k_ropevt(ushort* __restrict__ Q, ushort* __restrict__ Kv,
              const ushort* __restrict__ Vb, ushort* __restrict__ VbT,
              const float* __restrict__ cosT, const float* __restrict__ sinT) {
    __shared__ __align__(16) ushort t[64 * 72];
    int blk = blockIdx.x;
    int tid = threadIdx.x;
    if (blk < 32768) {
        int wid  = (blk * 256 + tid) >> 6;
        int lane = tid & 63;
        int s  = wid & (S_ - 1);
        int bh = wid >> 11;
        int i  = lane & 31;
        float c  = cosT[s * 32 + i];
        float sn = sinT[s * 32 + i];
        size_t base = ((size_t)bh * S_ + s) * HD_;

        uint32_t uq = *(const uint32_t*)&Q[base + 2 * i];
        float x1 = u2f(uq << 16), x2 = u2f(uq & 0xFFFF0000u);
        float o  = (lane < 32) ? (x1 * c - x2 * sn) : (x1 * sn + x2 * c);
        Q[base + lane] = f2bf(o * 0.1803368801f);   // (1/8)*log2(e)

        uint32_t uk = *(const uint32_t*)&Kv[base + 2 * i];
        x1 = u2f(uk << 16); x2 = u2f(uk & 0xFFFF0000u);
        o  = (lane < 32) ? (x1 * c - x2 * sn) : (x1 * sn + x2 * c);
        Kv[base + lane] = f2bf(o);
        return;
    }
    int b2 = blk - 32768;
    int bh = b2 >> 5;
    int s0 = (b2 & 31) * 64;
    int ss = tid >> 2, c0 = (tid & 3) * 16;
    size_t base = (size_t)bh * S_ * HD_;
    *(uint4*)&t[ss * 72 + c0]     = *(const uint4*)&Vb[base + (size_t)(s0 + ss) * HD_ + c0];
    *(uint4*)&t[ss * 72 + c0 + 8] = *(const uint4*)&Vb[base + (size_t)(s0 + ss) * HD_ + c0 + 8];
    __syncthreads();
    int hd = tid >> 2, q0 = (tid & 3) * 16;
    ushort tmp[16];
    #pragma unroll
    for (int e = 0; e < 16; e++) tmp[e] = t[(q0 + e) * 72 + hd];
    size_t obase = (size_t)bh * HD_ * S_ + (size_t)hd * S_ + s0 + q0;
    *(uint4*)&VbT[obase]     = *(const uint4*)&tmp[0];
    *(uint4*)&VbT[obase + 8] = *(const uint4*)&tmp[8];
}

// ---------------------------------------------------------------- flash attention v11
// Post-mortem v9/v10: any inner-loop restructure that grows per-wave live
// state past ~104 unified regs spills to scratch (WRITE_SIZE +20MB). v11 is
// the v8 (round-0, 84us) inner loop UNTOUCHED register-wise; the change is
// the work decomposition:
//  - 32 strips of 64 q-rows. Block p in [0,16) owns strip sA=p (light) as
//    m=0 and strip sB=31-p (heavy) as m=1, nk = sB+1 tiles. Light strip's
//    act[0] turns off halfway; every block does exactly 33 compute-units
//    per wave -> zero within-CU tail (v8's stratum {32,26,6,4}-tile blocks
//    left the CU running 1 block for the back half: Occupancy 31%).
//  - v_cvt_pk_bf16_f32 pack (2 ops vs 4 add + 2 perm), RNE.
//  - s_setprio(1) around MFMA clusters (T5).
// grid: 1024 blocks = 16 pairs x 64 bh (bh in low bits: all 16 blocks of a
// bh land on XCD bh%8 -> 8 bh x 512KB = 4MB K/V per XCD L2). 256 threads.
__global__ __launch_bounds__(256, 4)
void k_attn(const ushort* __restrict__ Q, const ushort* __restrict__ K,
            const ushort* __restrict__ VT, ushort* __restrict__ O) {
    __shared__ __align__(16) ushort Ks[64 * 64];       // [key][hd]  swizzled
    __shared__ __align__(16) ushort Vt[64 * 64];       // [hd][key]  swizzled
    __shared__ __align__(16) ushort Pst[4][32 * 64];   // per-wave [qrow][key] swizzled

    int tid  = threadIdx.x;
    int lane = tid & 63;
    int wave = tid >> 6;
    int quad = lane >> 4;
    int l16  = lane & 15;

    int bh   = blockIdx.x & 63;
    int p    = blockIdx.x >> 6;          // pair index 0..15
    int sA   = p;                        // light strip (64 rows)
    int sB   = 31 - p;                   // heavy strip (64 rows)
    size_t hbase = (size_t)bh * S_ * HD_;
    size_t vbase = (size_t)bh * HD_ * S_;

    int mrow[2] = { sA * 64 + wave * 16, sB * 64 + wave * 16 };

    short8 qf[2][2];
    #pragma unroll
    for (int m = 0; m < 2; m++)
        #pragma unroll
        for (int h = 0; h < 2; h++)
            qf[m][h] = *(const short8*)&Q[hbase + (size_t)(mrow[m] + l16) * HD_ + quad * 8 + h * 32];

    short8 ones;
    #pragma unroll
    for (int e = 0; e < 8; e++) ones[e] = (short)0x3F80;   // bf16 1.0

    floatx4 acc[2][4] = {};
    floatx4 accl[2] = {};

    // staging pointers (advance by constant per tile)
    int c0r = tid >> 3;                     // chunk row for i=0 (0..31)
    int c1r = (256 + tid) >> 3;             // chunk row for i=1 (32..63)
    const ushort* kp0 = &K[hbase + (size_t)c0r * HD_ + (((tid & 7) ^ (c0r & 7)) << 3)];
    const ushort* kp1 = &K[hbase + (size_t)c1r * HD_ + (((tid & 7) ^ (c1r & 7)) << 3)];
    const ushort* vp0 = &VT[vbase + (size_t)c0r * S_ + (((tid & 7) ^ (c0r & 7)) << 3)];
    const ushort* vp1 = &VT[vbase + (size_t)c1r * S_ + (((tid & 7) ^ (c1r & 7)) << 3)];

    int nk = sB + 1;
    for (int kb = 0; kb < nk; kb++) {
        int k0 = kb * 64;
        __syncthreads();
        gl_lds16(kp0, &Ks[tid * 8]);
        gl_lds16(kp1, &Ks[(256 + tid) * 8]);
        gl_lds16(vp0, &Vt[tid * 8]);
        gl_lds16(vp1, &Vt[(256 + tid) * 8]);
        kp0 += 64 * HD_; kp1 += 64 * HD_; vp0 += 64; vp1 += 64;
        __syncthreads();

        bool act[2] = { k0 <= mrow[0] + 15, k0 <= mrow[1] + 15 };

        // ---- QK + exp2 + packed swizzled P store (m sequential: sc[4] only)
        #pragma unroll
        for (int m = 0; m < 2; m++) {
            if (!act[m]) continue;
            floatx4 sc[4] = {};
            __builtin_amdgcn_s_setprio(1);
            #pragma unroll
            for (int kt = 0; kt < 4; kt++)
                #pragma unroll
                for (int h = 0; h < 2; h++) {
                    short8 kf = *(const short8*)&Ks[(kt * 16 + l16) * 64 +
                                                    (((h * 4 + quad) ^ (l16 & 7)) << 3)];
                    sc[kt] = __builtin_amdgcn_mfma_f32_16x16x32_bf16(kf, qf[m][h], sc[kt], 0, 0, 0);
                }
            __builtin_amdgcn_s_setprio(0);
            bool needMask = (k0 + 63 > mrow[m]);
            int qr = mrow[m] + l16;
            #pragma unroll
            for (int kt = 0; kt < 4; kt++) {
                float pp[4];
                #pragma unroll
                for (int r = 0; r < 4; r++) {
                    float v = exp2f(sc[kt][r]);
                    if (needMask) {
                        int kc = k0 + kt * 16 + quad * 4 + r;
                        if (kc > qr) v = 0.0f;
                    }
                    pp[r] = v;
                }
                uint2 pk;
                asm("v_cvt_pk_bf16_f32 %0, %1, %2" : "=v"(pk.x) : "v"(pp[0]), "v"(pp[1]));
                asm("v_cvt_pk_bf16_f32 %0, %1, %2" : "=v"(pk.y) : "v"(pp[2]), "v"(pp[3]));
                int pc = (kt * 4 + quad) ^ (l16 & 14);
                *(uint2*)&Pst[wave][(m * 16 + l16) * 64 + pc * 4] = pk;
            }
        }

        // ---- PV (+ MFMA-pipe row sums), vb shared across m
        #pragma unroll
        for (int k2 = 0; k2 < 2; k2++) {
            short8 vb[4];
            #pragma unroll
            for (int nt = 0; nt < 4; nt++)
                vb[nt] = *(const short8*)&Vt[(nt * 16 + l16) * 64 +
                                             (((k2 * 4 + quad) ^ (l16 & 7)) << 3)];
            int pe = (k2 * 8 + quad * 2) ^ (l16 & 14);
            __builtin_amdgcn_s_setprio(1);
            #pragma unroll
            for (int m = 0; m < 2; m++) {
                if (!act[m]) continue;
                short8 pa = *(const short8*)&Pst[wave][(m * 16 + l16) * 64 + pe * 4];
                #pragma unroll
                for (int nt = 0; nt < 4; nt++)
                    acc[m][nt] = __builtin_amdgcn_mfma_f32_16x16x32_bf16(pa, vb[nt], acc[m][nt], 0, 0, 0);
                accl[m] = __builtin_amdgcn_mfma_f32_16x16x32_bf16(pa, ones, accl[m], 0, 0, 0);
            }
            __builtin_amdgcn_s_setprio(0);
        }
    }

    int b = bh >> 4, h = bh & 15;
    #pragma unroll
    for (int m = 0; m < 2; m++)
        #pragma unroll
        for (int r = 0; r < 4; r++) {
            float inv = 1.0f / accl[m][r];
            int qr = mrow[m] + quad * 4 + r;
            #pragma unroll
            for (int nt = 0; nt < 4; nt++)
                O[((size_t)(b * S_ + qr)) * D_ + h * HD_ + nt * 16 + l16] = f2bf(acc[m][nt][r] * inv);
        }
}

// ---------------------------------------------------------------- launch
extern "C" void kernel_launch(void* const* d_in, const int* in_sizes, int n_in,
                              void* d_out, int out_size, void* d_ws, size_t ws_size,
                              hipStream_t stream) {
    const float* x    = (const float*)d_in[0];
    const float* cosT = (const float*)d_in[1];
    const float* sinT = (const float*)d_in[2];
    // d_in[3] = mask : causal, computed analytically — never read
    const float* Wqkv = (const float*)d_in[4];
    const float* Wout = (const float*)d_in[5];
    float* out = (float*)d_out;

    ushort* ws = (ushort*)d_ws;
    ushort* Xbf    = ws;                           // 8192*1024 (dead after GEMM0)
    ushort* WqkvT  = Xbf    + (size_t)MROWS * D_;  // 3072*1024
    ushort* WoutT  = WqkvT  + (size_t)3 * D_ * D_; // 1024*1024
    ushort* Qb     = WoutT  + (size_t)D_ * D_;     // 64*2048*64
    ushort* Kb     = Qb     + (size_t)BH_ * S_ * HD_;
    ushort* Vb     = Kb     + (size_t)BH_ * S_ * HD_;
    ushort* VbT    = Vb     + (size_t)BH_ * S_ * HD_;
    ushort* AO     = Xbf;                          // alias: Xbf dead after GEMM0

    k_prep<<<12288, 256, 0, stream>>>(x, Wqkv, Wout, Xbf, WqkvT, WoutT);
    k_gemm<0><<<dim3(3 * D_ / BN, MROWS / BM), 256, 0, stream>>>(Xbf, WqkvT, nullptr, Qb, Kb, Vb,
                                                                 MROWS, 3 * D_, D_);
    k_ropevt<<<34816, 256, 0, stream>>>(Qb, Kb, Vb, VbT, cosT, sinT);
    k_attn<<<1024, 256, 0, stream>>>(Qb, Kb, VbT, AO);
    k_gemm<1><<<dim3(D_ / BN, MROWS / BM), 256, 0, stream>>>(AO, WoutT, out, nullptr, nullptr, nullptr,
                                                             MROWS, D_, D_);
}

// Round 4
// 297.315 us; speedup vs baseline: 1.2867x; 1.0108x over previous
//
#include <hip/hip_runtime.h>
#include <hip/hip_bf16.h>
#include <stdint.h>

// Problem constants (hard-coded): B=4, S=2048, D=1024, H=16, HD=64
#define B_   4
#define S_   2048
#define D_   1024
#define H_   16
#define HD_  64
#define BH_  (B_*H_)      // 64
#define MROWS (B_*S_)     // 8192

typedef short  short8  __attribute__((ext_vector_type(8)));
typedef float  floatx4 __attribute__((ext_vector_type(4)));

__device__ __forceinline__ ushort f2bf(float f) {
    union { float f; uint32_t u; } v; v.f = f;
    uint32_t u = v.u;
    return (ushort)((u + 0x7FFFu + ((u >> 16) & 1u)) >> 16);   // RNE
}
__device__ __forceinline__ float u2f(uint32_t u) {
    union { uint32_t u; float f; } v; v.u = u; return v.f;
}
__device__ __forceinline__ uint32_t f2u(float f) {
    union { float f; uint32_t u; } v; v.f = f; return v.u;
}

// async global->LDS, 16 B per lane. LDS dest MUST be wave-uniform base +
// lane*16 (m104/m108) — any swizzling must happen on the GLOBAL address.
__device__ __forceinline__ void gl_lds16(const ushort* g, ushort* l) {
    __builtin_amdgcn_global_load_lds(
        (const __attribute__((address_space(1))) unsigned int*)g,
        (__attribute__((address_space(3))) unsigned int*)l,
        16, 0, 0);
}

// ---------------------------------------------------------------- fused prep
// blocks [0,3072): Wqkv^T->bf16 ; [3072,4096): Wout^T->bf16 ; [4096,12288): x->bf16
__global__ __launch_bounds__(256)
void k_prep(const float* __restrict__ x, const float* __restrict__ Wqkv,
            const float* __restrict__ Wout,
            ushort* __restrict__ Xbf, ushort* __restrict__ WqkvT, ushort* __restrict__ WoutT) {
    __shared__ float tile[32][33];
    int blk = blockIdx.x;
    int tid = threadIdx.x;
    if (blk >= 4096) {
        int i = (blk - 4096) * 1024 + tid * 4;
        float4 f = *(const float4*)(x + i);
        ushort4 o; o.x = f2bf(f.x); o.y = f2bf(f.y); o.z = f2bf(f.z); o.w = f2bf(f.w);
        *(ushort4*)(Xbf + i) = o;
        return;
    }
    const float* in; ushort* out; int R, C, bx, by;
    if (blk < 3072) { in = Wqkv; out = WqkvT; R = D_; C = 3 * D_; bx = (blk % 96) * 32; by = (blk / 96) * 32; }
    else            { int b2 = blk - 3072; in = Wout; out = WoutT; R = D_; C = D_; bx = (b2 % 32) * 32; by = (b2 / 32) * 32; }
    int tx = tid & 31, ty = tid >> 5;
    #pragma unroll
    for (int j = 0; j < 32; j += 8)
        tile[ty + j][tx] = in[(size_t)(by + ty + j) * C + bx + tx];
    __syncthreads();
    #pragma unroll
    for (int j = 0; j < 32; j += 8)
        out[(size_t)(bx + ty + j) * R + by + tx] = f2bf(tile[tx][ty + j]);
}

// ---------------------------------------------------------------- GEMM (async + global-side XOR swizzle)
#define BM 128
#define BN 128
#define BK 64

template<int EPI>
__global__ __launch_bounds__(256)
void k_gemm(const ushort* __restrict__ A, const ushort* __restrict__ Bt,
            float* __restrict__ outF,
            ushort* __restrict__ q_out, ushort* __restrict__ k_out, ushort* __restrict__ v_out,
            int M, int N, int K) {
    __shared__ __align__(16) ushort As[BM * 64];
    __shared__ __align__(16) ushort Bs[BN * 64];
    int tid  = threadIdx.x;
    int lane = tid & 63;
    int wave = tid >> 6;
    int quad = lane >> 4;
    int l16  = lane & 15;
    int bm = blockIdx.y * BM;
    int bn = blockIdx.x * BN;
    int wm = (wave >> 1) * 64;
    int wn = (wave & 1) * 64;

    floatx4 acc[4][4] = {};

    for (int k0 = 0; k0 < K; k0 += BK) {
        __syncthreads();
        #pragma unroll
        for (int i = 0; i < 4; i++) {
            int c   = i * 256 + tid;
            int row = c >> 3;
            int gc  = (c & 7) ^ (row & 7);    // permuted global chunk
            gl_lds16(&A[(size_t)(bm + row) * K + k0 + gc * 8],  &As[c * 8]);
            gl_lds16(&Bt[(size_t)(bn + row) * K + k0 + gc * 8], &Bs[c * 8]);
        }
        __syncthreads();
        #pragma unroll
        for (int kk = 0; kk < 2; kk++) {
            short8 af[4], bf[4];
            #pragma unroll
            for (int mt = 0; mt < 4; mt++)
                af[mt] = *(const short8*)&As[(wm + mt * 16 + l16) * 64 +
                                             (((kk * 4 + quad) ^ (l16 & 7)) << 3)];
            #pragma unroll
            for (int nt = 0; nt < 4; nt++)
                bf[nt] = *(const short8*)&Bs[(wn + nt * 16 + l16) * 64 +
                                             (((kk * 4 + quad) ^ (l16 & 7)) << 3)];
            #pragma unroll
            for (int mt = 0; mt < 4; mt++)
                #pragma unroll
                for (int nt = 0; nt < 4; nt++)
                    acc[mt][nt] = __builtin_amdgcn_mfma_f32_16x16x32_bf16(af[mt], bf[nt], acc[mt][nt], 0, 0, 0);
        }
    }

    #pragma unroll
    for (int mt = 0; mt < 4; mt++)
        #pragma unroll
        for (int nt = 0; nt < 4; nt++)
            #pragma unroll
            for (int r = 0; r < 4; r++) {
                int row = bm + wm + mt * 16 + quad * 4 + r;
                int col = bn + wn + nt * 16 + l16;
                float v = acc[mt][nt][r];
                if (EPI == 0) {
                    int which = col >> 10;
                    int rem   = col & 1023;
                    int h  = rem >> 6, hd = rem & 63;
                    int b  = row >> 11, s  = row & 2047;
                    size_t idx = ((size_t)(b * H_ + h) * S_ + s) * HD_ + hd;
                    ushort bv = f2bf(v);
                    ushort* dst = (which == 0) ? q_out : (which == 1) ? k_out : v_out;
                    dst[idx] = bv;
                } else {
                    outF[(size_t)row * N + col] = v;
                }
            }
}

// ---------------------------------------------------------------- fused RoPE + V-transpose
// blocks [0,32768): in-place RoPE on Q (pre-scaled by 0.125*log2(e)) and K.
// blocks [32768,34816): V [bh][s][HD] -> VbT [bh][HD][S].
__global__ __launch_bounds__(256)
void k_ropevt(ushort* __restrict__ Q, ushort* __restrict__ Kv,
              const ushort* __restrict__ Vb, ushort* __restrict__ VbT,
              const float* __restrict__ cosT, const float* __restrict__ sinT) {
    __shared__ __align__(16) ushort t[64 * 72];
    int blk = blockIdx.x;
    int tid = threadIdx.x;
    if (blk < 32768) {
        int wid  = (blk * 256 + tid) >> 6;
        int lane = tid & 63;
        int s  = wid & (S_ - 1);
        int bh = wid >> 11;
        int i  = lane & 31;
        float c  = cosT[s * 32 + i];
        float sn = sinT[s * 32 + i];
        size_t base = ((size_t)bh * S_ + s) * HD_;

        uint32_t uq = *(const uint32_t*)&Q[base + 2 * i];
        float x1 = u2f(uq << 16), x2 = u2f(uq & 0xFFFF0000u);
        float o  = (lane < 32) ? (x1 * c - x2 * sn) : (x1 * sn + x2 * c);
        Q[base + lane] = f2bf(o * 0.1803368801f);   // (1/8)*log2(e)

        uint32_t uk = *(const uint32_t*)&Kv[base + 2 * i];
        x1 = u2f(uk << 16); x2 = u2f(uk & 0xFFFF0000u);
        o  = (lane < 32) ? (x1 * c - x2 * sn) : (x1 * sn + x2 * c);
        Kv[base + lane] = f2bf(o);
        return;
    }
    int b2 = blk - 32768;
    int bh = b2 >> 5;
    int s0 = (b2 & 31) * 64;
    int ss = tid >> 2, c0 = (tid & 3) * 16;
    size_t base = (size_t)bh * S_ * HD_;
    *(uint4*)&t[ss * 72 + c0]     = *(const uint4*)&Vb[base + (size_t)(s0 + ss) * HD_ + c0];
    *(uint4*)&t[ss * 72 + c0 + 8] = *(const uint4*)&Vb[base + (size_t)(s0 + ss) * HD_ + c0 + 8];
    __syncthreads();
    int hd = tid >> 2, q0 = (tid & 3) * 16;
    ushort tmp[16];
    #pragma unroll
    for (int e = 0; e < 16; e++) tmp[e] = t[(q0 + e) * 72 + hd];
    size_t obase = (size_t)bh * HD_ * S_ + (size_t)hd * S_ + s0 + q0;
    *(uint4*)&VbT[obase]     = *(const uint4*)&tmp[0];
    *(uint4*)&VbT[obase + 8] = *(const uint4*)&tmp[8];
}

// ---------------------------------------------------------------- flash attention v12
// Post-mortem v11 (79.6us): no pipe saturated; LDS ~65% busy (36KB/wave-tile
// at 69TB/s ceiling = 52us), VALU 60% (48us), MFMA 21%. Biggest LDS item: kf
// fragments read TWICE (once per m) because QK was m-sequential. But this
// kernel has NO running max — softmax is elementwise exp2 + MFMA row-sum —
// so per-m sequencing is unnecessary. v12:
//  - kt-outer QK: each kf pair (h=0,1) loaded ONCE from LDS, feeds both m's
//    MFMAs; exp2+pack fused per (m,kt) with a single floatx4 sc live
//    (4 regs, LESS pressure than v11's sc[4]). kf reads 16->8 b128/tile:
//    LDS traffic 36->28 KB/wave-tile (-22%).
//  - raw __builtin_amdgcn_exp2f (1 instr) replaces exp2f's OCML wrapper.
//  - hoisted z4 zero C-operand kills 32 v_mov sc-inits per tile.
//  - __builtin_amdgcn_rcpf in epilogue.
// PV, staging, barriers, balanced (sA, 31-sA) pairing, grid: identical v11.
__global__ __launch_bounds__(256, 4)
void k_attn(const ushort* __restrict__ Q, const ushort* __restrict__ K,
            const ushort* __restrict__ VT, ushort* __restrict__ O) {
    __shared__ __align__(16) ushort Ks[64 * 64];       // [key][hd]  swizzled
    __shared__ __align__(16) ushort Vt[64 * 64];       // [hd][key]  swizzled
    __shared__ __align__(16) ushort Pst[4][32 * 64];   // per-wave [qrow][key] swizzled

    int tid  = threadIdx.x;
    int lane = tid & 63;
    int wave = tid >> 6;
    int quad = lane >> 4;
    int l16  = lane & 15;

    int bh   = blockIdx.x & 63;
    int p    = blockIdx.x >> 6;          // pair index 0..15
    int sA   = p;                        // light strip (64 rows)
    int sB   = 31 - p;                   // heavy strip (64 rows)
    size_t hbase = (size_t)bh * S_ * HD_;
    size_t vbase = (size_t)bh * HD_ * S_;

    int mrow[2] = { sA * 64 + wave * 16, sB * 64 + wave * 16 };

    short8 qf[2][2];
    #pragma unroll
    for (int m = 0; m < 2; m++)
        #pragma unroll
        for (int h = 0; h < 2; h++)
            qf[m][h] = *(const short8*)&Q[hbase + (size_t)(mrow[m] + l16) * HD_ + quad * 8 + h * 32];

    short8 ones;
    #pragma unroll
    for (int e = 0; e < 8; e++) ones[e] = (short)0x3F80;   // bf16 1.0

    floatx4 acc[2][4] = {};
    floatx4 accl[2] = {};
    const floatx4 z4 = {0.f, 0.f, 0.f, 0.f};

    // staging pointers (advance by constant per tile)
    int c0r = tid >> 3;                     // chunk row for i=0 (0..31)
    int c1r = (256 + tid) >> 3;             // chunk row for i=1 (32..63)
    const ushort* kp0 = &K[hbase + (size_t)c0r * HD_ + (((tid & 7) ^ (c0r & 7)) << 3)];
    const ushort* kp1 = &K[hbase + (size_t)c1r * HD_ + (((tid & 7) ^ (c1r & 7)) << 3)];
    const ushort* vp0 = &VT[vbase + (size_t)c0r * S_ + (((tid & 7) ^ (c0r & 7)) << 3)];
    const ushort* vp1 = &VT[vbase + (size_t)c1r * S_ + (((tid & 7) ^ (c1r & 7)) << 3)];

    int nk = sB + 1;
    for (int kb = 0; kb < nk; kb++) {
        int k0 = kb * 64;
        __syncthreads();
        gl_lds16(kp0, &Ks[tid * 8]);
        gl_lds16(kp1, &Ks[(256 + tid) * 8]);
        gl_lds16(vp0, &Vt[tid * 8]);
        gl_lds16(vp1, &Vt[(256 + tid) * 8]);
        kp0 += 64 * HD_; kp1 += 64 * HD_; vp0 += 64; vp1 += 64;
        __syncthreads();

        bool act0 = (k0 <= mrow[0] + 15);    // m=1 always active inside loop

        // ---- QK kt-outer: kf loaded once, shared across m; exp2+pack fused
        #pragma unroll
        for (int kt = 0; kt < 4; kt++) {
            short8 kf0 = *(const short8*)&Ks[(kt * 16 + l16) * 64 + ((quad ^ (l16 & 7)) << 3)];
            short8 kf1 = *(const short8*)&Ks[(kt * 16 + l16) * 64 + (((4 + quad) ^ (l16 & 7)) << 3)];

            __builtin_amdgcn_s_setprio(1);
            floatx4 s1 = __builtin_amdgcn_mfma_f32_16x16x32_bf16(kf0, qf[1][0], z4, 0, 0, 0);
            s1         = __builtin_amdgcn_mfma_f32_16x16x32_bf16(kf1, qf[1][1], s1, 0, 0, 0);
            floatx4 s0 = z4;
            if (act0) {
                s0 = __builtin_amdgcn_mfma_f32_16x16x32_bf16(kf0, qf[0][0], z4, 0, 0, 0);
                s0 = __builtin_amdgcn_mfma_f32_16x16x32_bf16(kf1, qf[0][1], s0, 0, 0, 0);
            }
            __builtin_amdgcn_s_setprio(0);

            int pc = (kt * 4 + quad) ^ (l16 & 14);
            #pragma unroll
            for (int m = 0; m < 2; m++) {
                if (m == 0 && !act0) continue;
                floatx4 sm = (m == 0) ? s0 : s1;
                bool needMask = (k0 + 63 > mrow[m]);
                int qr = mrow[m] + l16;
                float pp[4];
                #pragma unroll
                for (int r = 0; r < 4; r++) {
                    float v = __builtin_amdgcn_exp2f(sm[r]);
                    if (needMask) {
                        int kc = k0 + kt * 16 + quad * 4 + r;
                        if (kc > qr) v = 0.0f;
                    }
                    pp[r] = v;
                }
                uint2 pk;
                asm("v_cvt_pk_bf16_f32 %0, %1, %2" : "=v"(pk.x) : "v"(pp[0]), "v"(pp[1]));
                asm("v_cvt_pk_bf16_f32 %0, %1, %2" : "=v"(pk.y) : "v"(pp[2]), "v"(pp[3]));
                *(uint2*)&Pst[wave][(m * 16 + l16) * 64 + pc * 4] = pk;
            }
        }

        // ---- PV (+ MFMA-pipe row sums), vb shared across m
        bool act[2] = { act0, true };
        #pragma unroll
        for (int k2 = 0; k2 < 2; k2++) {
            short8 vb[4];
            #pragma unroll
            for (int nt = 0; nt < 4; nt++)
                vb[nt] = *(const short8*)&Vt[(nt * 16 + l16) * 64 +
                                             (((k2 * 4 + quad) ^ (l16 & 7)) << 3)];
            int pe = (k2 * 8 + quad * 2) ^ (l16 & 14);
            __builtin_amdgcn_s_setprio(1);
            #pragma unroll
            for (int m = 0; m < 2; m++) {
                if (!act[m]) continue;
                short8 pa = *(const short8*)&Pst[wave][(m * 16 + l16) * 64 + pe * 4];
                #pragma unroll
                for (int nt = 0; nt < 4; nt++)
                    acc[m][nt] = __builtin_amdgcn_mfma_f32_16x16x32_bf16(pa, vb[nt], acc[m][nt], 0, 0, 0);
                accl[m] = __builtin_amdgcn_mfma_f32_16x16x32_bf16(pa, ones, accl[m], 0, 0, 0);
            }
            __builtin_amdgcn_s_setprio(0);
        }
    }

    int b = bh >> 4, h = bh & 15;
    #pragma unroll
    for (int m = 0; m < 2; m++)
        #pragma unroll
        for (int r = 0; r < 4; r++) {
            float inv = __builtin_amdgcn_rcpf(accl[m][r]);
            int qr = mrow[m] + quad * 4 + r;
            #pragma unroll
            for (int nt = 0; nt < 4; nt++)
                O[((size_t)(b * S_ + qr)) * D_ + h * HD_ + nt * 16 + l16] = f2bf(acc[m][nt][r] * inv);
        }
}

// ---------------------------------------------------------------- launch
extern "C" void kernel_launch(void* const* d_in, const int* in_sizes, int n_in,
                              void* d_out, int out_size, void* d_ws, size_t ws_size,
                              hipStream_t stream) {
    const float* x    = (const float*)d_in[0];
    const float* cosT = (const float*)d_in[1];
    const float* sinT = (const float*)d_in[2];
    // d_in[3] = mask : causal, computed analytically — never read
    const float* Wqkv = (const float*)d_in[4];
    const float* Wout = (const float*)d_in[5];
    float* out = (float*)d_out;

    ushort* ws = (ushort*)d_ws;
    ushort* Xbf    = ws;                           // 8192*1024 (dead after GEMM0)
    ushort* WqkvT  = Xbf    + (size_t)MROWS * D_;  // 3072*1024
    ushort* WoutT  = WqkvT  + (size_t)3 * D_ * D_; // 1024*1024
    ushort* Qb     = WoutT  + (size_t)D_ * D_;     // 64*2048*64
    ushort* Kb     = Qb     + (size_t)BH_ * S_ * HD_;
    ushort* Vb     = Kb     + (size_t)BH_ * S_ * HD_;
    ushort* VbT    = Vb     + (size_t)BH_ * S_ * HD_;
    ushort* AO     = Xbf;                          // alias: Xbf dead after GEMM0

    k_prep<<<12288, 256, 0, stream>>>(x, Wqkv, Wout, Xbf, WqkvT, WoutT);
    k_gemm<0><<<dim3(3 * D_ / BN, MROWS / BM), 256, 0, stream>>>(Xbf, WqkvT, nullptr, Qb, Kb, Vb,
                                                                 MROWS, 3 * D_, D_);
    k_ropevt<<<34816, 256, 0, stream>>>(Qb, Kb, Vb, VbT, cosT, sinT);
    k_attn<<<1024, 256, 0, stream>>>(Qb, Kb, VbT, AO);
    k_gemm<1><<<dim3(D_ / BN, MROWS / BM), 256, 0, stream>>>(AO, WoutT, out, nullptr, nullptr, nullptr,
                                                             MROWS, D_, D_);
}

// Round 5
// 294.382 us; speedup vs baseline: 1.2995x; 1.0100x over previous
//
#include <hip/hip_runtime.h>
#include <hip/hip_bf16.h>
#include <stdint.h>

// Problem constants (hard-coded): B=4, S=2048, D=1024, H=16, HD=64
#define B_   4
#define S_   2048
#define D_   1024
#define H_   16
#define HD_  64
#define BH_  (B_*H_)      // 64
#define MROWS (B_*S_)     // 8192

typedef short  short8  __attribute__((ext_vector_type(8)));
typedef float  floatx4 __attribute__((ext_vector_type(4)));

__device__ __forceinline__ ushort f2bf(float f) {
    union { float f; uint32_t u; } v; v.f = f;
    uint32_t u = v.u;
    return (ushort)((u + 0x7FFFu + ((u >> 16) & 1u)) >> 16);   // RNE
}
__device__ __forceinline__ float u2f(uint32_t u) {
    union { uint32_t u; float f; } v; v.u = u; return v.f;
}
__device__ __forceinline__ uint32_t f2u(float f) {
    union { float f; uint32_t u; } v; v.f = f; return v.u;
}

// async global->LDS, 16 B per lane. LDS dest MUST be wave-uniform base +
// lane*16 (m104/m108) — any swizzling must happen on the GLOBAL address.
__device__ __forceinline__ void gl_lds16(const ushort* g, ushort* l) {
    __builtin_amdgcn_global_load_lds(
        (const __attribute__((address_space(1))) unsigned int*)g,
        (__attribute__((address_space(3))) unsigned int*)l,
        16, 0, 0);
}

// ---------------------------------------------------------------- fused prep
// blocks [0,3072): Wqkv^T->bf16 ; [3072,4096): Wout^T->bf16 ; [4096,12288): x->bf16
__global__ __launch_bounds__(256)
void k_prep(const float* __restrict__ x, const float* __restrict__ Wqkv,
            const float* __restrict__ Wout,
            ushort* __restrict__ Xbf, ushort* __restrict__ WqkvT, ushort* __restrict__ WoutT) {
    __shared__ float tile[32][33];
    int blk = blockIdx.x;
    int tid = threadIdx.x;
    if (blk >= 4096) {
        int i = (blk - 4096) * 1024 + tid * 4;
        float4 f = *(const float4*)(x + i);
        ushort4 o; o.x = f2bf(f.x); o.y = f2bf(f.y); o.z = f2bf(f.z); o.w = f2bf(f.w);
        *(ushort4*)(Xbf + i) = o;
        return;
    }
    const float* in; ushort* out; int R, C, bx, by;
    if (blk < 3072) { in = Wqkv; out = WqkvT; R = D_; C = 3 * D_; bx = (blk % 96) * 32; by = (blk / 96) * 32; }
    else            { int b2 = blk - 3072; in = Wout; out = WoutT; R = D_; C = D_; bx = (b2 % 32) * 32; by = (b2 / 32) * 32; }
    int tx = tid & 31, ty = tid >> 5;
    #pragma unroll
    for (int j = 0; j < 32; j += 8)
        tile[ty + j][tx] = in[(size_t)(by + ty + j) * C + bx + tx];
    __syncthreads();
    #pragma unroll
    for (int j = 0; j < 32; j += 8)
        out[(size_t)(bx + ty + j) * R + by + tx] = f2bf(tile[tx][ty + j]);
}

// ---------------------------------------------------------------- GEMM (async + global-side XOR swizzle)
#define BM 128
#define BN 128
#define BK 64

template<int EPI>
__global__ __launch_bounds__(256)
void k_gemm(const ushort* __restrict__ A, const ushort* __restrict__ Bt,
            float* __restrict__ outF,
            ushort* __restrict__ q_out, ushort* __restrict__ k_out, ushort* __restrict__ v_out,
            int M, int N, int K) {
    __shared__ __align__(16) ushort As[BM * 64];
    __shared__ __align__(16) ushort Bs[BN * 64];
    int tid  = threadIdx.x;
    int lane = tid & 63;
    int wave = tid >> 6;
    int quad = lane >> 4;
    int l16  = lane & 15;
    int bm = blockIdx.y * BM;
    int bn = blockIdx.x * BN;
    int wm = (wave >> 1) * 64;
    int wn = (wave & 1) * 64;

    floatx4 acc[4][4] = {};

    for (int k0 = 0; k0 < K; k0 += BK) {
        __syncthreads();
        #pragma unroll
        for (int i = 0; i < 4; i++) {
            int c   = i * 256 + tid;
            int row = c >> 3;
            int gc  = (c & 7) ^ (row & 7);    // permuted global chunk
            gl_lds16(&A[(size_t)(bm + row) * K + k0 + gc * 8],  &As[c * 8]);
            gl_lds16(&Bt[(size_t)(bn + row) * K + k0 + gc * 8], &Bs[c * 8]);
        }
        __syncthreads();
        #pragma unroll
        for (int kk = 0; kk < 2; kk++) {
            short8 af[4], bf[4];
            #pragma unroll
            for (int mt = 0; mt < 4; mt++)
                af[mt] = *(const short8*)&As[(wm + mt * 16 + l16) * 64 +
                                             (((kk * 4 + quad) ^ (l16 & 7)) << 3)];
            #pragma unroll
            for (int nt = 0; nt < 4; nt++)
                bf[nt] = *(const short8*)&Bs[(wn + nt * 16 + l16) * 64 +
                                             (((kk * 4 + quad) ^ (l16 & 7)) << 3)];
            #pragma unroll
            for (int mt = 0; mt < 4; mt++)
                #pragma unroll
                for (int nt = 0; nt < 4; nt++)
                    acc[mt][nt] = __builtin_amdgcn_mfma_f32_16x16x32_bf16(af[mt], bf[nt], acc[mt][nt], 0, 0, 0);
        }
    }

    #pragma unroll
    for (int mt = 0; mt < 4; mt++)
        #pragma unroll
        for (int nt = 0; nt < 4; nt++)
            #pragma unroll
            for (int r = 0; r < 4; r++) {
                int row = bm + wm + mt * 16 + quad * 4 + r;
                int col = bn + wn + nt * 16 + l16;
                float v = acc[mt][nt][r];
                if (EPI == 0) {
                    int which = col >> 10;
                    int rem   = col & 1023;
                    int h  = rem >> 6, hd = rem & 63;
                    int b  = row >> 11, s  = row & 2047;
                    size_t idx = ((size_t)(b * H_ + h) * S_ + s) * HD_ + hd;
                    ushort bv = f2bf(v);
                    ushort* dst = (which == 0) ? q_out : (which == 1) ? k_out : v_out;
                    dst[idx] = bv;
                } else {
                    outF[(size_t)row * N + col] = v;
                }
            }
}

// ---------------------------------------------------------------- fused RoPE + V-transpose
// blocks [0,32768): in-place RoPE on Q (pre-scaled by 0.125*log2(e)) and K.
// blocks [32768,34816): V [bh][s][HD] -> VbT [bh][HD][S].
__global__ __launch_bounds__(256)
void k_ropevt(ushort* __restrict__ Q, ushort* __restrict__ Kv,
              const ushort* __restrict__ Vb, ushort* __restrict__ VbT,
              const float* __restrict__ cosT, const float* __restrict__ sinT) {
    __shared__ __align__(16) ushort t[64 * 72];
    int blk = blockIdx.x;
    int tid = threadIdx.x;
    if (blk < 32768) {
        int wid  = (blk * 256 + tid) >> 6;
        int lane = tid & 63;
        int s  = wid & (S_ - 1);
        int bh = wid >> 11;
        int i  = lane & 31;
        float c  = cosT[s * 32 + i];
        float sn = sinT[s * 32 + i];
        size_t base = ((size_t)bh * S_ + s) * HD_;

        uint32_t uq = *(const uint32_t*)&Q[base + 2 * i];
        float x1 = u2f(uq << 16), x2 = u2f(uq & 0xFFFF0000u);
        float o  = (lane < 32) ? (x1 * c - x2 * sn) : (x1 * sn + x2 * c);
        Q[base + lane] = f2bf(o * 0.1803368801f);   // (1/8)*log2(e)

        uint32_t uk = *(const uint32_t*)&Kv[base + 2 * i];
        x1 = u2f(uk << 16); x2 = u2f(uk & 0xFFFF0000u);
        o  = (lane < 32) ? (x1 * c - x2 * sn) : (x1 * sn + x2 * c);
        Kv[base + lane] = f2bf(o);
        return;
    }
    int b2 = blk - 32768;
    int bh = b2 >> 5;
    int s0 = (b2 & 31) * 64;
    int ss = tid >> 2, c0 = (tid & 3) * 16;
    size_t base = (size_t)bh * S_ * HD_;
    *(uint4*)&t[ss * 72 + c0]     = *(const uint4*)&Vb[base + (size_t)(s0 + ss) * HD_ + c0];
    *(uint4*)&t[ss * 72 + c0 + 8] = *(const uint4*)&Vb[base + (size_t)(s0 + ss) * HD_ + c0 + 8];
    __syncthreads();
    int hd = tid >> 2, q0 = (tid & 3) * 16;
    ushort tmp[16];
    #pragma unroll
    for (int e = 0; e < 16; e++) tmp[e] = t[(q0 + e) * 72 + hd];
    size_t obase = (size_t)bh * HD_ * S_ + (size_t)hd * S_ + s0 + q0;
    *(uint4*)&VbT[obase]     = *(const uint4*)&tmp[0];
    *(uint4*)&VbT[obase + 8] = *(const uint4*)&tmp[8];
}

// ---------------------------------------------------------------- flash attention v13
// Post-mortem v12 (66us): VALU 47% + MFMA 28%, LDS ~50%, no pipe saturated ->
// ~25% of cycles issue nothing. Candidate: staging latency exposed between
// the two barriers (global_load_lds -> vmcnt(0) drain at 2nd barrier) with
// only ~2.7 blocks/CU to cover it. v13 = T14 async-STAGE split (m214 v27,
// measured +17% on attn): prefetch next tile into REGISTERS during compute,
// ds_write after the barrier. Loads' vmcnt wait lands at the NEXT
// iteration's ds_write, after a full compute phase; only ds_write latency
// stays exposed. LDS stays 32KB (same buffers); +16 VGPR (4x uint4).
// Compute section identical to v12 (kt-outer QK, raw exp2, z4, cvt_pk).
__global__ __launch_bounds__(256, 4)
void k_attn(const ushort* __restrict__ Q, const ushort* __restrict__ K,
            const ushort* __restrict__ VT, ushort* __restrict__ O) {
    __shared__ __align__(16) ushort Ks[64 * 64];       // [key][hd]  swizzled
    __shared__ __align__(16) ushort Vt[64 * 64];       // [hd][key]  swizzled
    __shared__ __align__(16) ushort Pst[4][32 * 64];   // per-wave [qrow][key] swizzled

    int tid  = threadIdx.x;
    int lane = tid & 63;
    int wave = tid >> 6;
    int quad = lane >> 4;
    int l16  = lane & 15;

    int bh   = blockIdx.x & 63;
    int p    = blockIdx.x >> 6;          // pair index 0..15
    int sA   = p;                        // light strip (64 rows)
    int sB   = 31 - p;                   // heavy strip (64 rows)
    size_t hbase = (size_t)bh * S_ * HD_;
    size_t vbase = (size_t)bh * HD_ * S_;

    int mrow[2] = { sA * 64 + wave * 16, sB * 64 + wave * 16 };

    short8 qf[2][2];
    #pragma unroll
    for (int m = 0; m < 2; m++)
        #pragma unroll
        for (int h = 0; h < 2; h++)
            qf[m][h] = *(const short8*)&Q[hbase + (size_t)(mrow[m] + l16) * HD_ + quad * 8 + h * 32];

    short8 ones;
    #pragma unroll
    for (int e = 0; e < 8; e++) ones[e] = (short)0x3F80;   // bf16 1.0

    floatx4 acc[2][4] = {};
    floatx4 accl[2] = {};
    const floatx4 z4 = {0.f, 0.f, 0.f, 0.f};

    // staging pointers (advance by constant per tile)
    int c0r = tid >> 3;                     // chunk row for i=0 (0..31)
    int c1r = (256 + tid) >> 3;             // chunk row for i=1 (32..63)
    const ushort* kp0 = &K[hbase + (size_t)c0r * HD_ + (((tid & 7) ^ (c0r & 7)) << 3)];
    const ushort* kp1 = &K[hbase + (size_t)c1r * HD_ + (((tid & 7) ^ (c1r & 7)) << 3)];
    const ushort* vp0 = &VT[vbase + (size_t)c0r * S_ + (((tid & 7) ^ (c0r & 7)) << 3)];
    const ushort* vp1 = &VT[vbase + (size_t)c1r * S_ + (((tid & 7) ^ (c1r & 7)) << 3)];

    int nk = sB + 1;

    // prologue: tile 0 -> regs; pointers advance to tile 1
    uint4 rk0 = *(const uint4*)kp0;
    uint4 rk1 = *(const uint4*)kp1;
    uint4 rv0 = *(const uint4*)vp0;
    uint4 rv1 = *(const uint4*)vp1;
    kp0 += 64 * HD_; kp1 += 64 * HD_; vp0 += 64; vp1 += 64;

    for (int kb = 0; kb < nk; kb++) {
        int k0 = kb * 64;
        __syncthreads();                 // everyone done computing tile kb-1
        // write staged regs (tile kb) into LDS
        *(uint4*)&Ks[tid * 8]         = rk0;
        *(uint4*)&Ks[(256 + tid) * 8] = rk1;
        *(uint4*)&Vt[tid * 8]         = rv0;
        *(uint4*)&Vt[(256 + tid) * 8] = rv1;
        if (kb + 1 < nk) {               // issue tile kb+1 loads; they land
            rk0 = *(const uint4*)kp0;    // during this tile's compute
            rk1 = *(const uint4*)kp1;
            rv0 = *(const uint4*)vp0;
            rv1 = *(const uint4*)vp1;
            kp0 += 64 * HD_; kp1 += 64 * HD_; vp0 += 64; vp1 += 64;
        }
        __syncthreads();                 // tile kb visible in LDS

        bool act0 = (k0 <= mrow[0] + 15);    // m=1 always active inside loop

        // ---- QK kt-outer: kf loaded once, shared across m; exp2+pack fused
        #pragma unroll
        for (int kt = 0; kt < 4; kt++) {
            short8 kf0 = *(const short8*)&Ks[(kt * 16 + l16) * 64 + ((quad ^ (l16 & 7)) << 3)];
            short8 kf1 = *(const short8*)&Ks[(kt * 16 + l16) * 64 + (((4 + quad) ^ (l16 & 7)) << 3)];

            __builtin_amdgcn_s_setprio(1);
            floatx4 s1 = __builtin_amdgcn_mfma_f32_16x16x32_bf16(kf0, qf[1][0], z4, 0, 0, 0);
            s1         = __builtin_amdgcn_mfma_f32_16x16x32_bf16(kf1, qf[1][1], s1, 0, 0, 0);
            floatx4 s0 = z4;
            if (act0) {
                s0 = __builtin_amdgcn_mfma_f32_16x16x32_bf16(kf0, qf[0][0], z4, 0, 0, 0);
                s0 = __builtin_amdgcn_mfma_f32_16x16x32_bf16(kf1, qf[0][1], s0, 0, 0, 0);
            }
            __builtin_amdgcn_s_setprio(0);

            int pc = (kt * 4 + quad) ^ (l16 & 14);
            #pragma unroll
            for (int m = 0; m < 2; m++) {
                if (m == 0 && !act0) continue;
                floatx4 sm = (m == 0) ? s0 : s1;
                bool needMask = (k0 + 63 > mrow[m]);
                int qr = mrow[m] + l16;
                float pp[4];
                #pragma unroll
                for (int r = 0; r < 4; r++) {
                    float v = __builtin_amdgcn_exp2f(sm[r]);
                    if (needMask) {
                        int kc = k0 + kt * 16 + quad * 4 + r;
                        if (kc > qr) v = 0.0f;
                    }
                    pp[r] = v;
                }
                uint2 pk;
                asm("v_cvt_pk_bf16_f32 %0, %1, %2" : "=v"(pk.x) : "v"(pp[0]), "v"(pp[1]));
                asm("v_cvt_pk_bf16_f32 %0, %1, %2" : "=v"(pk.y) : "v"(pp[2]), "v"(pp[3]));
                *(uint2*)&Pst[wave][(m * 16 + l16) * 64 + pc * 4] = pk;
            }
        }

        // ---- PV (+ MFMA-pipe row sums), vb shared across m
        bool act[2] = { act0, true };
        #pragma unroll
        for (int k2 = 0; k2 < 2; k2++) {
            short8 vb[4];
            #pragma unroll
            for (int nt = 0; nt < 4; nt++)
                vb[nt] = *(const short8*)&Vt[(nt * 16 + l16) * 64 +
                                             (((k2 * 4 + quad) ^ (l16 & 7)) << 3)];
            int pe = (k2 * 8 + quad * 2) ^ (l16 & 14);
            __builtin_amdgcn_s_setprio(1);
            #pragma unroll
            for (int m = 0; m < 2; m++) {
                if (!act[m]) continue;
                short8 pa = *(const short8*)&Pst[wave][(m * 16 + l16) * 64 + pe * 4];
                #pragma unroll
                for (int nt = 0; nt < 4; nt++)
                    acc[m][nt] = __builtin_amdgcn_mfma_f32_16x16x32_bf16(pa, vb[nt], acc[m][nt], 0, 0, 0);
                accl[m] = __builtin_amdgcn_mfma_f32_16x16x32_bf16(pa, ones, accl[m], 0, 0, 0);
            }
            __builtin_amdgcn_s_setprio(0);
        }
    }

    int b = bh >> 4, h = bh & 15;
    #pragma unroll
    for (int m = 0; m < 2; m++)
        #pragma unroll
        for (int r = 0; r < 4; r++) {
            float inv = __builtin_amdgcn_rcpf(accl[m][r]);
            int qr = mrow[m] + quad * 4 + r;
            #pragma unroll
            for (int nt = 0; nt < 4; nt++)
                O[((size_t)(b * S_ + qr)) * D_ + h * HD_ + nt * 16 + l16] = f2bf(acc[m][nt][r] * inv);
        }
}

// ---------------------------------------------------------------- launch
extern "C" void kernel_launch(void* const* d_in, const int* in_sizes, int n_in,
                              void* d_out, int out_size, void* d_ws, size_t ws_size,
                              hipStream_t stream) {
    const float* x    = (const float*)d_in[0];
    const float* cosT = (const float*)d_in[1];
    const float* sinT = (const float*)d_in[2];
    // d_in[3] = mask : causal, computed analytically — never read
    const float* Wqkv = (const float*)d_in[4];
    const float* Wout = (const float*)d_in[5];
    float* out = (float*)d_out;

    ushort* ws = (ushort*)d_ws;
    ushort* Xbf    = ws;                           // 8192*1024 (dead after GEMM0)
    ushort* WqkvT  = Xbf    + (size_t)MROWS * D_;  // 3072*1024
    ushort* WoutT  = WqkvT  + (size_t)3 * D_ * D_; // 1024*1024
    ushort* Qb     = WoutT  + (size_t)D_ * D_;     // 64*2048*64
    ushort* Kb     = Qb     + (size_t)BH_ * S_ * HD_;
    ushort* Vb     = Kb     + (size_t)BH_ * S_ * HD_;
    ushort* VbT    = Vb     + (size_t)BH_ * S_ * HD_;
    ushort* AO     = Xbf;                          // alias: Xbf dead after GEMM0

    k_prep<<<12288, 256, 0, stream>>>(x, Wqkv, Wout, Xbf, WqkvT, WoutT);
    k_gemm<0><<<dim3(3 * D_ / BN, MROWS / BM), 256, 0, stream>>>(Xbf, WqkvT, nullptr, Qb, Kb, Vb,
                                                                 MROWS, 3 * D_, D_);
    k_ropevt<<<34816, 256, 0, stream>>>(Qb, Kb, Vb, VbT, cosT, sinT);
    k_attn<<<1024, 256, 0, stream>>>(Qb, Kb, VbT, AO);
    k_gemm<1><<<dim3(D_ / BN, MROWS / BM), 256, 0, stream>>>(AO, WoutT, out, nullptr, nullptr, nullptr,
                                                             MROWS, D_, D_);
}

// Round 6
// 290.726 us; speedup vs baseline: 1.3159x; 1.0126x over previous
//
#include <hip/hip_runtime.h>
#include <hip/hip_bf16.h>
#include <stdint.h>

// Problem constants (hard-coded): B=4, S=2048, D=1024, H=16, HD=64
#define B_   4
#define S_   2048
#define D_   1024
#define H_   16
#define HD_  64
#define BH_  (B_*H_)      // 64
#define MROWS (B_*S_)     // 8192

typedef short  short8  __attribute__((ext_vector_type(8)));
typedef float  floatx4 __attribute__((ext_vector_type(4)));

__device__ __forceinline__ ushort f2bf(float f) {
    union { float f; uint32_t u; } v; v.f = f;
    uint32_t u = v.u;
    return (ushort)((u + 0x7FFFu + ((u >> 16) & 1u)) >> 16);   // RNE
}
__device__ __forceinline__ float u2f(uint32_t u) {
    union { uint32_t u; float f; } v; v.u = u; return v.f;
}
__device__ __forceinline__ uint32_t f2u(float f) {
    union { float f; uint32_t u; } v; v.f = f; return v.u;
}

// async global->LDS, 16 B per lane. LDS dest MUST be wave-uniform base +
// lane*16 (m104/m108) — any swizzling must happen on the GLOBAL address.
__device__ __forceinline__ void gl_lds16(const ushort* g, ushort* l) {
    __builtin_amdgcn_global_load_lds(
        (const __attribute__((address_space(1))) unsigned int*)g,
        (__attribute__((address_space(3))) unsigned int*)l,
        16, 0, 0);
}

// ---------------------------------------------------------------- fused prep
// blocks [0,3072): Wqkv^T->bf16 ; [3072,4096): Wout^T->bf16 ; [4096,12288): x->bf16
__global__ __launch_bounds__(256)
void k_prep(const float* __restrict__ x, const float* __restrict__ Wqkv,
            const float* __restrict__ Wout,
            ushort* __restrict__ Xbf, ushort* __restrict__ WqkvT, ushort* __restrict__ WoutT) {
    __shared__ float tile[32][33];
    int blk = blockIdx.x;
    int tid = threadIdx.x;
    if (blk >= 4096) {
        int i = (blk - 4096) * 1024 + tid * 4;
        float4 f = *(const float4*)(x + i);
        ushort4 o; o.x = f2bf(f.x); o.y = f2bf(f.y); o.z = f2bf(f.z); o.w = f2bf(f.w);
        *(ushort4*)(Xbf + i) = o;
        return;
    }
    const float* in; ushort* out; int R, C, bx, by;
    if (blk < 3072) { in = Wqkv; out = WqkvT; R = D_; C = 3 * D_; bx = (blk % 96) * 32; by = (blk / 96) * 32; }
    else            { int b2 = blk - 3072; in = Wout; out = WoutT; R = D_; C = D_; bx = (b2 % 32) * 32; by = (b2 / 32) * 32; }
    int tx = tid & 31, ty = tid >> 5;
    #pragma unroll
    for (int j = 0; j < 32; j += 8)
        tile[ty + j][tx] = in[(size_t)(by + ty + j) * C + bx + tx];
    __syncthreads();
    #pragma unroll
    for (int j = 0; j < 32; j += 8)
        out[(size_t)(bx + ty + j) * R + by + tx] = f2bf(tile[tx][ty + j]);
}

// ---------------------------------------------------------------- GEMM (async + global-side XOR swizzle)
// v6 epilogue (EPI=0): acc -> LDS bounce (stride-132 pad) -> fused RoPE on
// q/k + coalesced uint4 stores. Replaces 64 scalar 2B scattered stores per
// thread AND eliminates the separate RoPE kernel's 64MB round-trip.
// Numerics identical to old path: rope reads the same post-f2bf bf16 values.
#define BM 128
#define BN 128
#define BK 64

template<int EPI>
__global__ __launch_bounds__(256)
void k_gemm(const ushort* __restrict__ A, const ushort* __restrict__ Bt,
            float* __restrict__ outF,
            ushort* __restrict__ q_out, ushort* __restrict__ k_out, ushort* __restrict__ v_out,
            int M, int N, int K,
            const float* __restrict__ cosT, const float* __restrict__ sinT) {
    __shared__ __align__(16) ushort smem[128 * 132];   // 33 KB: K-loop uses first 32KB as As|Bs
    ushort* As = smem;
    ushort* Bs = smem + BM * 64;
    int tid  = threadIdx.x;
    int lane = tid & 63;
    int wave = tid >> 6;
    int quad = lane >> 4;
    int l16  = lane & 15;
    int bm = blockIdx.y * BM;
    int bn = blockIdx.x * BN;
    int wm = (wave >> 1) * 64;
    int wn = (wave & 1) * 64;

    floatx4 acc[4][4] = {};

    for (int k0 = 0; k0 < K; k0 += BK) {
        __syncthreads();
        #pragma unroll
        for (int i = 0; i < 4; i++) {
            int c   = i * 256 + tid;
            int row = c >> 3;
            int gc  = (c & 7) ^ (row & 7);    // permuted global chunk
            gl_lds16(&A[(size_t)(bm + row) * K + k0 + gc * 8],  &As[c * 8]);
            gl_lds16(&Bt[(size_t)(bn + row) * K + k0 + gc * 8], &Bs[c * 8]);
        }
        __syncthreads();
        #pragma unroll
        for (int kk = 0; kk < 2; kk++) {
            short8 af[4], bf[4];
            #pragma unroll
            for (int mt = 0; mt < 4; mt++)
                af[mt] = *(const short8*)&As[(wm + mt * 16 + l16) * 64 +
                                             (((kk * 4 + quad) ^ (l16 & 7)) << 3)];
            #pragma unroll
            for (int nt = 0; nt < 4; nt++)
                bf[nt] = *(const short8*)&Bs[(wn + nt * 16 + l16) * 64 +
                                             (((kk * 4 + quad) ^ (l16 & 7)) << 3)];
            #pragma unroll
            for (int mt = 0; mt < 4; mt++)
                #pragma unroll
                for (int nt = 0; nt < 4; nt++)
                    acc[mt][nt] = __builtin_amdgcn_mfma_f32_16x16x32_bf16(af[mt], bf[nt], acc[mt][nt], 0, 0, 0);
        }
    }

    if (EPI == 1) {
        #pragma unroll
        for (int mt = 0; mt < 4; mt++)
            #pragma unroll
            for (int nt = 0; nt < 4; nt++)
                #pragma unroll
                for (int r = 0; r < 4; r++) {
                    int row = bm + wm + mt * 16 + quad * 4 + r;
                    int col = bn + wn + nt * 16 + l16;
                    outF[(size_t)row * N + col] = acc[mt][nt][r];
                }
        return;
    }

    // ---- EPI==0: LDS bounce + fused RoPE + coalesced stores
    __syncthreads();                     // K-loop reads of As/Bs done
    #pragma unroll
    for (int mt = 0; mt < 4; mt++)
        #pragma unroll
        for (int nt = 0; nt < 4; nt++)
            #pragma unroll
            for (int r = 0; r < 4; r++) {
                int srow = wm + mt * 16 + quad * 4 + r;
                int scol = wn + nt * 16 + l16;
                smem[srow * 132 + scol] = f2bf(acc[mt][nt][r]);
            }
    __syncthreads();

    int which = bn >> 10;                // block-uniform: 0=q 1=k 2=v
    ushort* dst = (which == 0) ? q_out : (which == 1) ? k_out : v_out;
    int hbase2 = (bn & 1023) >> 6;       // head at cc=0

    #pragma unroll
    for (int i = 0; i < 8; i++) {
        int g    = i * 256 + tid;
        int srow = g >> 4;               // 0..127
        int cc   = (g & 15) * 8;         // 0..120
        int s    = bm + srow;
        int b    = s >> 11, sloc = s & 2047;
        int h    = hbase2 + (cc >> 6);
        int hd0  = cc & 63;
        size_t didx = ((size_t)((b * H_ + h) * S_ + sloc)) * HD_ + hd0;

        if (which == 2) {                // V: plain copy
            uint2 a0 = *(const uint2*)&smem[srow * 132 + cc];
            uint2 a1 = *(const uint2*)&smem[srow * 132 + cc + 4];
            uint4 o4 = make_uint4(a0.x, a0.y, a1.x, a1.y);
            *(uint4*)&dst[didx] = o4;
        } else {                         // Q/K: rope inline
            int  i0 = cc & 31;
            bool up = (cc & 32) != 0;
            int  cb = cc & ~63;
            const ushort* in = &smem[srow * 132 + cb + 2 * i0];
            uint2 wA = *(const uint2*)&in[0];
            uint2 wB = *(const uint2*)&in[4];
            uint2 wC = *(const uint2*)&in[8];
            uint2 wD = *(const uint2*)&in[12];
            uint32_t w[8] = { wA.x, wA.y, wB.x, wB.y, wC.x, wC.y, wD.x, wD.y };
            float cs[8], sn[8];
            *(float4*)&cs[0] = *(const float4*)&cosT[sloc * 32 + i0];
            *(float4*)&cs[4] = *(const float4*)&cosT[sloc * 32 + i0 + 4];
            *(float4*)&sn[0] = *(const float4*)&sinT[sloc * 32 + i0];
            *(float4*)&sn[4] = *(const float4*)&sinT[sloc * 32 + i0 + 4];
            ushort o[8];
            #pragma unroll
            for (int e = 0; e < 8; e++) {
                float x1 = u2f(w[e] << 16);
                float x2 = u2f(w[e] & 0xFFFF0000u);
                float ov = up ? (x1 * sn[e] + x2 * cs[e]) : (x1 * cs[e] - x2 * sn[e]);
                if (which == 0) ov *= 0.1803368801f;   // (1/8)*log2(e)
                o[e] = f2bf(ov);
            }
            *(uint4*)&dst[didx] = *(uint4*)o;
        }
    }
}

// ---------------------------------------------------------------- V-transpose only
// V [bh][s][HD] -> VbT [bh][HD][S].  (RoPE now fused into k_gemm<0> epilogue.)
__global__ __launch_bounds__(256)
void k_vt(const ushort* __restrict__ Vb, ushort* __restrict__ VbT) {
    __shared__ __align__(16) ushort t[64 * 72];
    int blk = blockIdx.x;
    int tid = threadIdx.x;
    int bh = blk >> 5;
    int s0 = (blk & 31) * 64;
    int ss = tid >> 2, c0 = (tid & 3) * 16;
    size_t base = (size_t)bh * S_ * HD_;
    *(uint4*)&t[ss * 72 + c0]     = *(const uint4*)&Vb[base + (size_t)(s0 + ss) * HD_ + c0];
    *(uint4*)&t[ss * 72 + c0 + 8] = *(const uint4*)&Vb[base + (size_t)(s0 + ss) * HD_ + c0 + 8];
    __syncthreads();
    int hd = tid >> 2, q0 = (tid & 3) * 16;
    ushort tmp[16];
    #pragma unroll
    for (int e = 0; e < 16; e++) tmp[e] = t[(q0 + e) * 72 + hd];
    size_t obase = (size_t)bh * HD_ * S_ + (size_t)hd * S_ + s0 + q0;
    *(uint4*)&VbT[obase]     = *(const uint4*)&tmp[0];
    *(uint4*)&VbT[obase + 8] = *(const uint4*)&tmp[8];
}

// ---------------------------------------------------------------- flash attention v13 (unchanged)
__global__ __launch_bounds__(256, 4)
void k_attn(const ushort* __restrict__ Q, const ushort* __restrict__ K,
            const ushort* __restrict__ VT, ushort* __restrict__ O) {
    __shared__ __align__(16) ushort Ks[64 * 64];       // [key][hd]  swizzled
    __shared__ __align__(16) ushort Vt[64 * 64];       // [hd][key]  swizzled
    __shared__ __align__(16) ushort Pst[4][32 * 64];   // per-wave [qrow][key] swizzled

    int tid  = threadIdx.x;
    int lane = tid & 63;
    int wave = tid >> 6;
    int quad = lane >> 4;
    int l16  = lane & 15;

    int bh   = blockIdx.x & 63;
    int p    = blockIdx.x >> 6;          // pair index 0..15
    int sA   = p;                        // light strip (64 rows)
    int sB   = 31 - p;                   // heavy strip (64 rows)
    size_t hbase = (size_t)bh * S_ * HD_;
    size_t vbase = (size_t)bh * HD_ * S_;

    int mrow[2] = { sA * 64 + wave * 16, sB * 64 + wave * 16 };

    short8 qf[2][2];
    #pragma unroll
    for (int m = 0; m < 2; m++)
        #pragma unroll
        for (int h = 0; h < 2; h++)
            qf[m][h] = *(const short8*)&Q[hbase + (size_t)(mrow[m] + l16) * HD_ + quad * 8 + h * 32];

    short8 ones;
    #pragma unroll
    for (int e = 0; e < 8; e++) ones[e] = (short)0x3F80;   // bf16 1.0

    floatx4 acc[2][4] = {};
    floatx4 accl[2] = {};
    const floatx4 z4 = {0.f, 0.f, 0.f, 0.f};

    // staging pointers (advance by constant per tile)
    int c0r = tid >> 3;                     // chunk row for i=0 (0..31)
    int c1r = (256 + tid) >> 3;             // chunk row for i=1 (32..63)
    const ushort* kp0 = &K[hbase + (size_t)c0r * HD_ + (((tid & 7) ^ (c0r & 7)) << 3)];
    const ushort* kp1 = &K[hbase + (size_t)c1r * HD_ + (((tid & 7) ^ (c1r & 7)) << 3)];
    const ushort* vp0 = &VT[vbase + (size_t)c0r * S_ + (((tid & 7) ^ (c0r & 7)) << 3)];
    const ushort* vp1 = &VT[vbase + (size_t)c1r * S_ + (((tid & 7) ^ (c1r & 7)) << 3)];

    int nk = sB + 1;

    // prologue: tile 0 -> regs; pointers advance to tile 1
    uint4 rk0 = *(const uint4*)kp0;
    uint4 rk1 = *(const uint4*)kp1;
    uint4 rv0 = *(const uint4*)vp0;
    uint4 rv1 = *(const uint4*)vp1;
    kp0 += 64 * HD_; kp1 += 64 * HD_; vp0 += 64; vp1 += 64;

    for (int kb = 0; kb < nk; kb++) {
        int k0 = kb * 64;
        __syncthreads();                 // everyone done computing tile kb-1
        // write staged regs (tile kb) into LDS
        *(uint4*)&Ks[tid * 8]         = rk0;
        *(uint4*)&Ks[(256 + tid) * 8] = rk1;
        *(uint4*)&Vt[tid * 8]         = rv0;
        *(uint4*)&Vt[(256 + tid) * 8] = rv1;
        if (kb + 1 < nk) {               // issue tile kb+1 loads; they land
            rk0 = *(const uint4*)kp0;    // during this tile's compute
            rk1 = *(const uint4*)kp1;
            rv0 = *(const uint4*)vp0;
            rv1 = *(const uint4*)vp1;
            kp0 += 64 * HD_; kp1 += 64 * HD_; vp0 += 64; vp1 += 64;
        }
        __syncthreads();                 // tile kb visible in LDS

        bool act0 = (k0 <= mrow[0] + 15);    // m=1 always active inside loop

        // ---- QK kt-outer: kf loaded once, shared across m; exp2+pack fused
        #pragma unroll
        for (int kt = 0; kt < 4; kt++) {
            short8 kf0 = *(const short8*)&Ks[(kt * 16 + l16) * 64 + ((quad ^ (l16 & 7)) << 3)];
            short8 kf1 = *(const short8*)&Ks[(kt * 16 + l16) * 64 + (((4 + quad) ^ (l16 & 7)) << 3)];

            __builtin_amdgcn_s_setprio(1);
            floatx4 s1 = __builtin_amdgcn_mfma_f32_16x16x32_bf16(kf0, qf[1][0], z4, 0, 0, 0);
            s1         = __builtin_amdgcn_mfma_f32_16x16x32_bf16(kf1, qf[1][1], s1, 0, 0, 0);
            floatx4 s0 = z4;
            if (act0) {
                s0 = __builtin_amdgcn_mfma_f32_16x16x32_bf16(kf0, qf[0][0], z4, 0, 0, 0);
                s0 = __builtin_amdgcn_mfma_f32_16x16x32_bf16(kf1, qf[0][1], s0, 0, 0, 0);
            }
            __builtin_amdgcn_s_setprio(0);

            int pc = (kt * 4 + quad) ^ (l16 & 14);
            #pragma unroll
            for (int m = 0; m < 2; m++) {
                if (m == 0 && !act0) continue;
                floatx4 sm = (m == 0) ? s0 : s1;
                bool needMask = (k0 + 63 > mrow[m]);
                int qr = mrow[m] + l16;
                float pp[4];
                #pragma unroll
                for (int r = 0; r < 4; r++) {
                    float v = __builtin_amdgcn_exp2f(sm[r]);
                    if (needMask) {
                        int kc = k0 + kt * 16 + quad * 4 + r;
                        if (kc > qr) v = 0.0f;
                    }
                    pp[r] = v;
                }
                uint2 pk;
                asm("v_cvt_pk_bf16_f32 %0, %1, %2" : "=v"(pk.x) : "v"(pp[0]), "v"(pp[1]));
                asm("v_cvt_pk_bf16_f32 %0, %1, %2" : "=v"(pk.y) : "v"(pp[2]), "v"(pp[3]));
                *(uint2*)&Pst[wave][(m * 16 + l16) * 64 + pc * 4] = pk;
            }
        }

        // ---- PV (+ MFMA-pipe row sums), vb shared across m
        bool act[2] = { act0, true };
        #pragma unroll
        for (int k2 = 0; k2 < 2; k2++) {
            short8 vb[4];
            #pragma unroll
            for (int nt = 0; nt < 4; nt++)
                vb[nt] = *(const short8*)&Vt[(nt * 16 + l16) * 64 +
                                             (((k2 * 4 + quad) ^ (l16 & 7)) << 3)];
            int pe = (k2 * 8 + quad * 2) ^ (l16 & 14);
            __builtin_amdgcn_s_setprio(1);
            #pragma unroll
            for (int m = 0; m < 2; m++) {
                if (!act[m]) continue;
                short8 pa = *(const short8*)&Pst[wave][(m * 16 + l16) * 64 + pe * 4];
                #pragma unroll
                for (int nt = 0; nt < 4; nt++)
                    acc[m][nt] = __builtin_amdgcn_mfma_f32_16x16x32_bf16(pa, vb[nt], acc[m][nt], 0, 0, 0);
                accl[m] = __builtin_amdgcn_mfma_f32_16x16x32_bf16(pa, ones, accl[m], 0, 0, 0);
            }
            __builtin_amdgcn_s_setprio(0);
        }
    }

    int b = bh >> 4, h = bh & 15;
    #pragma unroll
    for (int m = 0; m < 2; m++)
        #pragma unroll
        for (int r = 0; r < 4; r++) {
            float inv = __builtin_amdgcn_rcpf(accl[m][r]);
            int qr = mrow[m] + quad * 4 + r;
            #pragma unroll
            for (int nt = 0; nt < 4; nt++)
                O[((size_t)(b * S_ + qr)) * D_ + h * HD_ + nt * 16 + l16] = f2bf(acc[m][nt][r] * inv);
        }
}

// ---------------------------------------------------------------- launch
extern "C" void kernel_launch(void* const* d_in, const int* in_sizes, int n_in,
                              void* d_out, int out_size, void* d_ws, size_t ws_size,
                              hipStream_t stream) {
    const float* x    = (const float*)d_in[0];
    const float* cosT = (const float*)d_in[1];
    const float* sinT = (const float*)d_in[2];
    // d_in[3] = mask : causal, computed analytically — never read
    const float* Wqkv = (const float*)d_in[4];
    const float* Wout = (const float*)d_in[5];
    float* out = (float*)d_out;

    ushort* ws = (ushort*)d_ws;
    ushort* Xbf    = ws;                           // 8192*1024 (dead after GEMM0)
    ushort* WqkvT  = Xbf    + (size_t)MROWS * D_;  // 3072*1024
    ushort* WoutT  = WqkvT  + (size_t)3 * D_ * D_; // 1024*1024
    ushort* Qb     = WoutT  + (size_t)D_ * D_;     // 64*2048*64
    ushort* Kb     = Qb     + (size_t)BH_ * S_ * HD_;
    ushort* Vb     = Kb     + (size_t)BH_ * S_ * HD_;
    ushort* VbT    = Vb     + (size_t)BH_ * S_ * HD_;
    ushort* AO     = Xbf;                          // alias: Xbf dead after GEMM0

    k_prep<<<12288, 256, 0, stream>>>(x, Wqkv, Wout, Xbf, WqkvT, WoutT);
    k_gemm<0><<<dim3(3 * D_ / BN, MROWS / BM), 256, 0, stream>>>(Xbf, WqkvT, nullptr, Qb, Kb, Vb,
                                                                 MROWS, 3 * D_, D_, cosT, sinT);
    k_vt<<<2048, 256, 0, stream>>>(Vb, VbT);
    k_attn<<<1024, 256, 0, stream>>>(Qb, Kb, VbT, AO);
    k_gemm<1><<<dim3(D_ / BN, MROWS / BM), 256, 0, stream>>>(AO, WoutT, out, nullptr, nullptr, nullptr,
                                                             MROWS, D_, D_, nullptr, nullptr);
}

// Round 7
// 286.870 us; speedup vs baseline: 1.3336x; 1.0134x over previous
//
#include <hip/hip_runtime.h>
#include <hip/hip_bf16.h>
#include <stdint.h>

// Problem constants (hard-coded): B=4, S=2048, D=1024, H=16, HD=64
#define B_   4
#define S_   2048
#define D_   1024
#define H_   16
#define HD_  64
#define BH_  (B_*H_)      // 64
#define MROWS (B_*S_)     // 8192

typedef short  short8  __attribute__((ext_vector_type(8)));
typedef float  floatx4 __attribute__((ext_vector_type(4)));

__device__ __forceinline__ ushort f2bf(float f) {
    union { float f; uint32_t u; } v; v.f = f;
    uint32_t u = v.u;
    return (ushort)((u + 0x7FFFu + ((u >> 16) & 1u)) >> 16);   // RNE
}
__device__ __forceinline__ float u2f(uint32_t u) {
    union { uint32_t u; float f; } v; v.u = u; return v.f;
}
__device__ __forceinline__ uint32_t f2u(float f) {
    union { float f; uint32_t u; } v; v.f = f; return v.u;
}

// async global->LDS, 16 B per lane. LDS dest MUST be wave-uniform base +
// lane*16 (m104/m108) — any swizzling must happen on the GLOBAL address.
__device__ __forceinline__ void gl_lds16(const ushort* g, ushort* l) {
    __builtin_amdgcn_global_load_lds(
        (const __attribute__((address_space(1))) unsigned int*)g,
        (__attribute__((address_space(3))) unsigned int*)l,
        16, 0, 0);
}

// ---------------------------------------------------------------- fused prep
// blocks [0,3072): Wqkv^T->bf16 ; [3072,4096): Wout^T->bf16 ; [4096,12288): x->bf16
__global__ __launch_bounds__(256)
void k_prep(const float* __restrict__ x, const float* __restrict__ Wqkv,
            const float* __restrict__ Wout,
            ushort* __restrict__ Xbf, ushort* __restrict__ WqkvT, ushort* __restrict__ WoutT) {
    __shared__ float tile[32][33];
    int blk = blockIdx.x;
    int tid = threadIdx.x;
    if (blk >= 4096) {
        int i = (blk - 4096) * 1024 + tid * 4;
        float4 f = *(const float4*)(x + i);
        ushort4 o; o.x = f2bf(f.x); o.y = f2bf(f.y); o.z = f2bf(f.z); o.w = f2bf(f.w);
        *(ushort4*)(Xbf + i) = o;
        return;
    }
    const float* in; ushort* out; int R, C, bx, by;
    if (blk < 3072) { in = Wqkv; out = WqkvT; R = D_; C = 3 * D_; bx = (blk % 96) * 32; by = (blk / 96) * 32; }
    else            { int b2 = blk - 3072; in = Wout; out = WoutT; R = D_; C = D_; bx = (b2 % 32) * 32; by = (b2 / 32) * 32; }
    int tx = tid & 31, ty = tid >> 5;
    #pragma unroll
    for (int j = 0; j < 32; j += 8)
        tile[ty + j][tx] = in[(size_t)(by + ty + j) * C + bx + tx];
    __syncthreads();
    #pragma unroll
    for (int j = 0; j < 32; j += 8)
        out[(size_t)(bx + ty + j) * R + by + tx] = f2bf(tile[tx][ty + j]);
}

// ---------------------------------------------------------------- GEMM (async + global-side XOR swizzle)
// EPI=0 epilogue: acc -> LDS bounce (stride-132 pad) ->
//   Q/K blocks: fused RoPE + coalesced uint4 stores.
//   V blocks:   DIRECT transposed write VbT[bh][hd][s] (column gather from
//               the bounce tile, 256B-contiguous lane-pair chunks) — V never
//               materializes row-major; k_vt kernel deleted.
#define BM 128
#define BN 128
#define BK 64

template<int EPI>
__global__ __launch_bounds__(256)
void k_gemm(const ushort* __restrict__ A, const ushort* __restrict__ Bt,
            float* __restrict__ outF,
            ushort* __restrict__ q_out, ushort* __restrict__ k_out, ushort* __restrict__ vT_out,
            int M, int N, int K,
            const float* __restrict__ cosT, const float* __restrict__ sinT) {
    __shared__ __align__(16) ushort smem[128 * 132];   // 33 KB: K-loop uses first 32KB as As|Bs
    ushort* As = smem;
    ushort* Bs = smem + BM * 64;
    int tid  = threadIdx.x;
    int lane = tid & 63;
    int wave = tid >> 6;
    int quad = lane >> 4;
    int l16  = lane & 15;
    int bm = blockIdx.y * BM;
    int bn = blockIdx.x * BN;
    int wm = (wave >> 1) * 64;
    int wn = (wave & 1) * 64;

    floatx4 acc[4][4] = {};

    for (int k0 = 0; k0 < K; k0 += BK) {
        __syncthreads();
        #pragma unroll
        for (int i = 0; i < 4; i++) {
            int c   = i * 256 + tid;
            int row = c >> 3;
            int gc  = (c & 7) ^ (row & 7);    // permuted global chunk
            gl_lds16(&A[(size_t)(bm + row) * K + k0 + gc * 8],  &As[c * 8]);
            gl_lds16(&Bt[(size_t)(bn + row) * K + k0 + gc * 8], &Bs[c * 8]);
        }
        __syncthreads();
        #pragma unroll
        for (int kk = 0; kk < 2; kk++) {
            short8 af[4], bf[4];
            #pragma unroll
            for (int mt = 0; mt < 4; mt++)
                af[mt] = *(const short8*)&As[(wm + mt * 16 + l16) * 64 +
                                             (((kk * 4 + quad) ^ (l16 & 7)) << 3)];
            #pragma unroll
            for (int nt = 0; nt < 4; nt++)
                bf[nt] = *(const short8*)&Bs[(wn + nt * 16 + l16) * 64 +
                                             (((kk * 4 + quad) ^ (l16 & 7)) << 3)];
            #pragma unroll
            for (int mt = 0; mt < 4; mt++)
                #pragma unroll
                for (int nt = 0; nt < 4; nt++)
                    acc[mt][nt] = __builtin_amdgcn_mfma_f32_16x16x32_bf16(af[mt], bf[nt], acc[mt][nt], 0, 0, 0);
        }
    }

    if (EPI == 1) {
        #pragma unroll
        for (int mt = 0; mt < 4; mt++)
            #pragma unroll
            for (int nt = 0; nt < 4; nt++)
                #pragma unroll
                for (int r = 0; r < 4; r++) {
                    int row = bm + wm + mt * 16 + quad * 4 + r;
                    int col = bn + wn + nt * 16 + l16;
                    outF[(size_t)row * N + col] = acc[mt][nt][r];
                }
        return;
    }

    // ---- EPI==0: LDS bounce, then fused RoPE (q/k) or direct V^T store
    __syncthreads();                     // K-loop reads of As/Bs done
    #pragma unroll
    for (int mt = 0; mt < 4; mt++)
        #pragma unroll
        for (int nt = 0; nt < 4; nt++)
            #pragma unroll
            for (int r = 0; r < 4; r++) {
                int srow = wm + mt * 16 + quad * 4 + r;
                int scol = wn + nt * 16 + l16;
                smem[srow * 132 + scol] = f2bf(acc[mt][nt][r]);
            }
    __syncthreads();

    int which  = bn >> 10;               // block-uniform: 0=q 1=k 2=v
    int hbase2 = (bn & 1023) >> 6;       // head at col 0 of tile
    int bIdx   = bm >> 11, sloc0 = bm & 2047;

    if (which == 2) {
        // V: column gather -> VbT[bh][hd][sloc0 .. sloc0+127]
        int c  = tid >> 1;               // tile column 0..127
        int hf = tid & 1;                // row half
        int h  = hbase2 + (c >> 6);
        int hd = c & 63;
        size_t obase = ((size_t)((bIdx * H_ + h) * HD_ + hd)) * S_ + sloc0 + hf * 64;
        #pragma unroll
        for (int j8 = 0; j8 < 8; j8++) {
            ushort t8[8];
            #pragma unroll
            for (int j = 0; j < 8; j++)
                t8[j] = smem[(hf * 64 + j8 * 8 + j) * 132 + c];
            *(uint4*)&vT_out[obase + j8 * 8] = *(uint4*)t8;
        }
        return;
    }

    ushort* dst = (which == 0) ? q_out : k_out;
    #pragma unroll
    for (int i = 0; i < 8; i++) {
        int g    = i * 256 + tid;
        int srow = g >> 4;               // 0..127
        int cc   = (g & 15) * 8;         // 0..120
        int sloc = sloc0 + srow;
        int h    = hbase2 + (cc >> 6);
        int hd0  = cc & 63;
        size_t didx = ((size_t)((bIdx * H_ + h) * S_ + sloc)) * HD_ + hd0;

        int  i0 = cc & 31;
        bool up = (cc & 32) != 0;
        int  cb = cc & ~63;
        const ushort* in = &smem[srow * 132 + cb + 2 * i0];
        uint2 wA = *(const uint2*)&in[0];
        uint2 wB = *(const uint2*)&in[4];
        uint2 wC = *(const uint2*)&in[8];
        uint2 wD = *(const uint2*)&in[12];
        uint32_t w[8] = { wA.x, wA.y, wB.x, wB.y, wC.x, wC.y, wD.x, wD.y };
        float cs[8], sn[8];
        *(float4*)&cs[0] = *(const float4*)&cosT[sloc * 32 + i0];
        *(float4*)&cs[4] = *(const float4*)&cosT[sloc * 32 + i0 + 4];
        *(float4*)&sn[0] = *(const float4*)&sinT[sloc * 32 + i0];
        *(float4*)&sn[4] = *(const float4*)&sinT[sloc * 32 + i0 + 4];
        ushort o[8];
        #pragma unroll
        for (int e = 0; e < 8; e++) {
            float x1 = u2f(w[e] << 16);
            float x2 = u2f(w[e] & 0xFFFF0000u);
            float ov = up ? (x1 * sn[e] + x2 * cs[e]) : (x1 * cs[e] - x2 * sn[e]);
            if (which == 0) ov *= 0.1803368801f;   // (1/8)*log2(e)
            o[e] = f2bf(ov);
        }
        *(uint4*)&dst[didx] = *(uint4*)o;
    }
}

// ---------------------------------------------------------------- flash attention v13 (unchanged)
__global__ __launch_bounds__(256, 4)
void k_attn(const ushort* __restrict__ Q, const ushort* __restrict__ K,
            const ushort* __restrict__ VT, ushort* __restrict__ O) {
    __shared__ __align__(16) ushort Ks[64 * 64];       // [key][hd]  swizzled
    __shared__ __align__(16) ushort Vt[64 * 64];       // [hd][key]  swizzled
    __shared__ __align__(16) ushort Pst[4][32 * 64];   // per-wave [qrow][key] swizzled

    int tid  = threadIdx.x;
    int lane = tid & 63;
    int wave = tid >> 6;
    int quad = lane >> 4;
    int l16  = lane & 15;

    int bh   = blockIdx.x & 63;
    int p    = blockIdx.x >> 6;          // pair index 0..15
    int sA   = p;                        // light strip (64 rows)
    int sB   = 31 - p;                   // heavy strip (64 rows)
    size_t hbase = (size_t)bh * S_ * HD_;
    size_t vbase = (size_t)bh * HD_ * S_;

    int mrow[2] = { sA * 64 + wave * 16, sB * 64 + wave * 16 };

    short8 qf[2][2];
    #pragma unroll
    for (int m = 0; m < 2; m++)
        #pragma unroll
        for (int h = 0; h < 2; h++)
            qf[m][h] = *(const short8*)&Q[hbase + (size_t)(mrow[m] + l16) * HD_ + quad * 8 + h * 32];

    short8 ones;
    #pragma unroll
    for (int e = 0; e < 8; e++) ones[e] = (short)0x3F80;   // bf16 1.0

    floatx4 acc[2][4] = {};
    floatx4 accl[2] = {};
    const floatx4 z4 = {0.f, 0.f, 0.f, 0.f};

    // staging pointers (advance by constant per tile)
    int c0r = tid >> 3;                     // chunk row for i=0 (0..31)
    int c1r = (256 + tid) >> 3;             // chunk row for i=1 (32..63)
    const ushort* kp0 = &K[hbase + (size_t)c0r * HD_ + (((tid & 7) ^ (c0r & 7)) << 3)];
    const ushort* kp1 = &K[hbase + (size_t)c1r * HD_ + (((tid & 7) ^ (c1r & 7)) << 3)];
    const ushort* vp0 = &VT[vbase + (size_t)c0r * S_ + (((tid & 7) ^ (c0r & 7)) << 3)];
    const ushort* vp1 = &VT[vbase + (size_t)c1r * S_ + (((tid & 7) ^ (c1r & 7)) << 3)];

    int nk = sB + 1;

    // prologue: tile 0 -> regs; pointers advance to tile 1
    uint4 rk0 = *(const uint4*)kp0;
    uint4 rk1 = *(const uint4*)kp1;
    uint4 rv0 = *(const uint4*)vp0;
    uint4 rv1 = *(const uint4*)vp1;
    kp0 += 64 * HD_; kp1 += 64 * HD_; vp0 += 64; vp1 += 64;

    for (int kb = 0; kb < nk; kb++) {
        int k0 = kb * 64;
        __syncthreads();                 // everyone done computing tile kb-1
        // write staged regs (tile kb) into LDS
        *(uint4*)&Ks[tid * 8]         = rk0;
        *(uint4*)&Ks[(256 + tid) * 8] = rk1;
        *(uint4*)&Vt[tid * 8]         = rv0;
        *(uint4*)&Vt[(256 + tid) * 8] = rv1;
        if (kb + 1 < nk) {               // issue tile kb+1 loads; they land
            rk0 = *(const uint4*)kp0;    // during this tile's compute
            rk1 = *(const uint4*)kp1;
            rv0 = *(const uint4*)vp0;
            rv1 = *(const uint4*)vp1;
            kp0 += 64 * HD_; kp1 += 64 * HD_; vp0 += 64; vp1 += 64;
        }
        __syncthreads();                 // tile kb visible in LDS

        bool act0 = (k0 <= mrow[0] + 15);    // m=1 always active inside loop

        // ---- QK kt-outer: kf loaded once, shared across m; exp2+pack fused
        #pragma unroll
        for (int kt = 0; kt < 4; kt++) {
            short8 kf0 = *(const short8*)&Ks[(kt * 16 + l16) * 64 + ((quad ^ (l16 & 7)) << 3)];
            short8 kf1 = *(const short8*)&Ks[(kt * 16 + l16) * 64 + (((4 + quad) ^ (l16 & 7)) << 3)];

            __builtin_amdgcn_s_setprio(1);
            floatx4 s1 = __builtin_amdgcn_mfma_f32_16x16x32_bf16(kf0, qf[1][0], z4, 0, 0, 0);
            s1         = __builtin_amdgcn_mfma_f32_16x16x32_bf16(kf1, qf[1][1], s1, 0, 0, 0);
            floatx4 s0 = z4;
            if (act0) {
                s0 = __builtin_amdgcn_mfma_f32_16x16x32_bf16(kf0, qf[0][0], z4, 0, 0, 0);
                s0 = __builtin_amdgcn_mfma_f32_16x16x32_bf16(kf1, qf[0][1], s0, 0, 0, 0);
            }
            __builtin_amdgcn_s_setprio(0);

            int pc = (kt * 4 + quad) ^ (l16 & 14);
            #pragma unroll
            for (int m = 0; m < 2; m++) {
                if (m == 0 && !act0) continue;
                floatx4 sm = (m == 0) ? s0 : s1;
                bool needMask = (k0 + 63 > mrow[m]);
                int qr = mrow[m] + l16;
                float pp[4];
                #pragma unroll
                for (int r = 0; r < 4; r++) {
                    float v = __builtin_amdgcn_exp2f(sm[r]);
                    if (needMask) {
                        int kc = k0 + kt * 16 + quad * 4 + r;
                        if (kc > qr) v = 0.0f;
                    }
                    pp[r] = v;
                }
                uint2 pk;
                asm("v_cvt_pk_bf16_f32 %0, %1, %2" : "=v"(pk.x) : "v"(pp[0]), "v"(pp[1]));
                asm("v_cvt_pk_bf16_f32 %0, %1, %2" : "=v"(pk.y) : "v"(pp[2]), "v"(pp[3]));
                *(uint2*)&Pst[wave][(m * 16 + l16) * 64 + pc * 4] = pk;
            }
        }

        // ---- PV (+ MFMA-pipe row sums), vb shared across m
        bool act[2] = { act0, true };
        #pragma unroll
        for (int k2 = 0; k2 < 2; k2++) {
            short8 vb[4];
            #pragma unroll
            for (int nt = 0; nt < 4; nt++)
                vb[nt] = *(const short8*)&Vt[(nt * 16 + l16) * 64 +
                                             (((k2 * 4 + quad) ^ (l16 & 7)) << 3)];
            int pe = (k2 * 8 + quad * 2) ^ (l16 & 14);
            __builtin_amdgcn_s_setprio(1);
            #pragma unroll
            for (int m = 0; m < 2; m++) {
                if (!act[m]) continue;
                short8 pa = *(const short8*)&Pst[wave][(m * 16 + l16) * 64 + pe * 4];
                #pragma unroll
                for (int nt = 0; nt < 4; nt++)
                    acc[m][nt] = __builtin_amdgcn_mfma_f32_16x16x32_bf16(pa, vb[nt], acc[m][nt], 0, 0, 0);
                accl[m] = __builtin_amdgcn_mfma_f32_16x16x32_bf16(pa, ones, accl[m], 0, 0, 0);
            }
            __builtin_amdgcn_s_setprio(0);
        }
    }

    int b = bh >> 4, h = bh & 15;
    #pragma unroll
    for (int m = 0; m < 2; m++)
        #pragma unroll
        for (int r = 0; r < 4; r++) {
            float inv = __builtin_amdgcn_rcpf(accl[m][r]);
            int qr = mrow[m] + quad * 4 + r;
            #pragma unroll
            for (int nt = 0; nt < 4; nt++)
                O[((size_t)(b * S_ + qr)) * D_ + h * HD_ + nt * 16 + l16] = f2bf(acc[m][nt][r] * inv);
        }
}

// ---------------------------------------------------------------- launch
extern "C" void kernel_launch(void* const* d_in, const int* in_sizes, int n_in,
                              void* d_out, int out_size, void* d_ws, size_t ws_size,
                              hipStream_t stream) {
    const float* x    = (const float*)d_in[0];
    const float* cosT = (const float*)d_in[1];
    const float* sinT = (const float*)d_in[2];
    // d_in[3] = mask : causal, computed analytically — never read
    const float* Wqkv = (const float*)d_in[4];
    const float* Wout = (const float*)d_in[5];
    float* out = (float*)d_out;

    ushort* ws = (ushort*)d_ws;
    ushort* Xbf    = ws;                           // 8192*1024 (dead after GEMM0)
    ushort* WqkvT  = Xbf    + (size_t)MROWS * D_;  // 3072*1024
    ushort* WoutT  = WqkvT  + (size_t)3 * D_ * D_; // 1024*1024
    ushort* Qb     = WoutT  + (size_t)D_ * D_;     // 64*2048*64
    ushort* Kb     = Qb     + (size_t)BH_ * S_ * HD_;
    ushort* VbT    = Kb     + (size_t)BH_ * S_ * HD_;   // V stored transposed directly
    ushort* AO     = Xbf;                          // alias: Xbf dead after GEMM0

    k_prep<<<12288, 256, 0, stream>>>(x, Wqkv, Wout, Xbf, WqkvT, WoutT);
    k_gemm<0><<<dim3(3 * D_ / BN, MROWS / BM), 256, 0, stream>>>(Xbf, WqkvT, nullptr, Qb, Kb, VbT,
                                                                 MROWS, 3 * D_, D_, cosT, sinT);
    k_attn<<<1024, 256, 0, stream>>>(Qb, Kb, VbT, AO);
    k_gemm<1><<<dim3(D_ / BN, MROWS / BM), 256, 0, stream>>>(AO, WoutT, out, nullptr, nullptr, nullptr,
                                                             MROWS, D_, D_, nullptr, nullptr);
}